// Round 12
// baseline (108.162 us; speedup 1.0000x reference)
//
#include <hip/hip_runtime.h>

// EuclidConv + BatchNorm (training stats), fp32 in/out.
// y = 2*conv(x,w) + t1 (+t2 cancels in BN).  bf16 MFMA implicit GEMM:
//   M=25088 pixels, N=256 chans, K=9 taps*128 ci.
// Round 12: drop the LDS A-slab; read A-frags DIRECTLY from global xp
// (XCD-L2-resident via swizzle; 16px x 64B fully-used lines). LDS shrinks to
// a two-pass 32x132 epilogue buffer (17.4KB); BN=64 + launch_bounds(256,4)
// targets <=128 VGPR -> 16 waves/CU (2x TLP vs slab design).

typedef short  bf16x8 __attribute__((ext_vector_type(8)));
typedef float  f32x4  __attribute__((ext_vector_type(4)));

#define NPIX   784
#define CI_    128
#define CO_    256
#define NB_    32
#define M_     25088
#define SHIFT_ 1152.0f
#define BN_EPS 1e-5f
#define M_TOT  25088

// ws layout (bytes): xp [32][30][30][128] bf16 = 7,372,800 ; s [32][30][30] f32 ;
// stats [2][256] f32 ; wp [36][16][4][16][8] bf16 = 589,824 (round-2 layout)
#define S_OFF   7372800
#define ST_OFF  7488000
#define WP_OFF  7490048
#define ZERO_F4 468128            // (ST_OFF + 2048) / 16 : zeroes xp + s + stats

__device__ __forceinline__ unsigned short f2bf(float f) {
    unsigned int u = __float_as_uint(f);
    unsigned int r = (u + 0x7FFFu + ((u >> 16) & 1u)) >> 16;
    return (unsigned short)r;
}

__global__ __launch_bounds__(256) void init_ws(float* ws) {
    int i = blockIdx.x * 256 + threadIdx.x;
    if (i < ZERO_F4) ((f32x4*)ws)[i] = (f32x4){0.f, 0.f, 0.f, 0.f};
}

// ---- pack x: NCHW f32 -> padded NHWC bf16, plus s = sum_ci x^2 (round-2) ----
__global__ __launch_bounds__(256) void pack_x(const float* __restrict__ x,
                                              unsigned short* __restrict__ xp,
                                              float* __restrict__ s) {
    const int n = blockIdx.x / 28, h = blockIdx.x % 28, tid = threadIdx.x;
    __shared__ float xs[128][29];
    __shared__ float part[8][28];

    #pragma unroll
    for (int i = 0; i < 14; ++i) {
        int e = tid + i * 256;
        int ci = e / 28, w = e - ci * 28;
        xs[ci][w] = x[(size_t)(n * 128 + ci) * 784 + h * 28 + w];
    }
    __syncthreads();
    #pragma unroll
    for (int i = 0; i < 14; ++i) {
        int e = tid + i * 256;
        int w = e >> 7, ci = e & 127;
        xp[((size_t)(n * 30 + h + 1) * 30 + (w + 1)) * 128 + ci] = f2bf(xs[ci][w]);
    }
    if (tid < 224) {
        int grp = tid / 28, w = tid - grp * 28;
        float a = 0.f;
        #pragma unroll
        for (int ci = grp * 16; ci < grp * 16 + 16; ++ci) a = fmaf(xs[ci][w], xs[ci][w], a);
        part[grp][w] = a;
    }
    __syncthreads();
    if (tid < 28) {
        float a = 0.f;
        #pragma unroll
        for (int g = 0; g < 8; ++g) a += part[g][tid];
        s[n * 900 + (h + 1) * 30 + (tid + 1)] = a;
    }
}

// ---- pack w (round-2 verified): wp[kblk(36)][ng(16)][kb(4)][cc(16)][k8(8)] ----
__global__ __launch_bounds__(256) void pack_w(const float* __restrict__ w,
                                              unsigned short* __restrict__ wp) {
    int o = blockIdx.x * 256 + threadIdx.x;      // < 294912
    int k8   = o & 7;
    int cc   = (o >> 3) & 15;
    int kb   = (o >> 7) & 3;
    int ng   = (o >> 9) & 15;
    int kblk = o >> 13;                          // 0..35
    int tap  = kblk >> 2;
    int ci   = (kblk & 3) * 32 + kb * 8 + k8;
    int co   = ng * 16 + cc;
    wp[o] = f2bf(w[(size_t)(co * 128 + ci) * 9 + tap]);
}

// ---- MFMA implicit GEMM: BM=128, BN=64, 4 waves (2x2 of 64x32) ----
// A direct-from-global (L2-hot xp), B direct-from-global (L2-hot wp).
// Small LDS (two-pass epilogue) -> 4 blocks/CU when VGPR <= 128.
__global__ __launch_bounds__(256, 4) void econv(
        const unsigned short* __restrict__ xp, const unsigned short* __restrict__ wp,
        const float* __restrict__ s, float* __restrict__ y, float* __restrict__ stats) {
    __shared__ float ldsT[32 * 132];   // 16,896 B (two-pass transpose buffer)
    __shared__ float t1s[128];

    const int tid = threadIdx.x;
    // XCD-aware bijective swizzle (784 = 8*98)
    int bid = blockIdx.x;
    int swz = (bid & 7) * 98 + (bid >> 3);
    const int nb = swz & 3;
    const int mb = swz >> 2;
    const int gblock = mb * 128;
    const int nblock = nb * 64;
    const int ng0 = nb * 4;

    // t1 = 3x3 box of padded per-pixel sum of x^2
    if (tid < 128) {
        int g = gblock + tid; int n = g / 784, p = g - n * 784;
        int h = p / 28, wq = p - h * 28;
        const float* sb = s + n * 900 + h * 30 + wq;
        t1s[tid] = (sb[0] + sb[1] + sb[2]) + (sb[30] + sb[31] + sb[32]) + (sb[60] + sb[61] + sb[62]);
    }

    const int lane = tid & 63;
    const int wid  = tid >> 6;
    const int wm = wid >> 1, wn = wid & 1;
    const int l15 = lane & 15, l16 = lane >> 4;

    // per-lane A base pointers: absolute padded pixel (3x3 window top-left)
    const unsigned short* xaf[4];
    #pragma unroll
    for (int fm = 0; fm < 4; ++fm) {
        int g = gblock + wm * 64 + fm * 16 + l15;
        int n = g / 784, p = g - n * 784;
        int h = p / 28, c = p - h * 28;
        xaf[fm] = xp + (size_t)((n * 30 + h) * 30 + c) * 128 + l16 * 8;
    }
    // per-lane B base: each wave's frag read is 1KB contiguous
    const unsigned short* wpl = wp + (size_t)((ng0 + wn * 2) * 64 + l16 * 16 + l15) * 8;

    f32x4 acc[4][2];
    #pragma unroll
    for (int a_ = 0; a_ < 4; ++a_)
        #pragma unroll
        for (int b_ = 0; b_ < 2; ++b_) acc[a_][b_] = (f32x4){0.f, 0.f, 0.f, 0.f};

    #pragma unroll
    for (int tap = 0; tap < 9; ++tap) {
        const int toff = ((tap / 3) * 30 + (tap % 3)) * 128;
        #pragma unroll
        for (int half = 0; half < 2; ++half) {
            bf16x8 aF[2][4], bF[2][2];
            #pragma unroll
            for (int q = 0; q < 2; ++q) {
                #pragma unroll
                for (int fm = 0; fm < 4; ++fm)
                    aF[q][fm] = *(const bf16x8*)&xaf[fm][toff + half * 64 + q * 32];
                const int K16 = (tap * 4 + half * 2 + q) * 16;
                #pragma unroll
                for (int fn = 0; fn < 2; ++fn)
                    bF[q][fn] = *(const bf16x8*)&wpl[(size_t)(K16 + fn) * 512];
            }
            #pragma unroll
            for (int q = 0; q < 2; ++q)
                #pragma unroll
                for (int fm = 0; fm < 4; ++fm)
                    #pragma unroll
                    for (int fn = 0; fn < 2; ++fn)
                        acc[fm][fn] = __builtin_amdgcn_mfma_f32_16x16x32_bf16(
                            aF[q][fm], bF[q][fn], acc[fm][fn], 0, 0, 0);
        }
    }

    // ---- epilogue: two-pass coalesced store via 32x132 LDS transpose ----
    float sSum[2] = {0.f, 0.f}, sSq[2] = {0.f, 0.f};
    #pragma unroll 1
    for (int pass = 0; pass < 2; ++pass) {
        __syncthreads();
        if (wn == pass) {
            #pragma unroll
            for (int fm = 0; fm < 4; ++fm) {
                #pragma unroll
                for (int j = 0; j < 4; ++j) {
                    int r = wm * 64 + fm * 16 + l16 * 4 + j;
                    float t1v = t1s[r];
                    #pragma unroll
                    for (int fn = 0; fn < 2; ++fn) {
                        float v = fmaf(2.f, acc[fm][fn][j], t1v);
                        ldsT[(fn * 16 + l15) * 132 + r] = v;
                        float d = v - SHIFT_;
                        sSum[fn] += d;
                        sSq[fn] = fmaf(d, d, sSq[fn]);
                    }
                }
            }
        }
        __syncthreads();
        #pragma unroll
        for (int i = 0; i < 4; ++i) {
            int idx = tid + i * 256;       // 0..1023
            int co  = idx >> 5;            // 0..31
            int r   = (idx & 31) * 4;      // block-local pixel, mult of 4
            int g   = gblock + r;
            int n = g / 784, p = g - n * 784;   // crossings at mult of 16: never split
            f32x4 v = *(const f32x4*)&ldsT[co * 132 + r];
            *(f32x4*)&y[(size_t)n * 200704 + (size_t)(nblock + pass * 32 + co) * 784 + p] = v;
        }
    }

    #pragma unroll
    for (int fn = 0; fn < 2; ++fn) {
        float a = sSum[fn], b2 = sSq[fn];
        a  += __shfl_xor(a, 16);  a  += __shfl_xor(a, 32);
        b2 += __shfl_xor(b2, 16); b2 += __shfl_xor(b2, 32);
        if (l16 == 0) {
            int co = nblock + wn * 32 + fn * 16 + l15;
            atomicAdd(&stats[co], a);
            atomicAdd(&stats[256 + co], b2);
        }
    }
}

__global__ __launch_bounds__(256) void bn_apply(
        float* __restrict__ y, const float* __restrict__ stats,
        const float* __restrict__ gamma, const float* __restrict__ beta) {
    const int TOTAL4 = NB_ * CO_ * NPIX / 4;
    int i4 = blockIdx.x * 256 + threadIdx.x;
    if (i4 >= TOTAL4) return;
    int c = (i4 / (NPIX / 4)) & (CO_ - 1);
    float su = stats[c];
    float s2 = stats[CO_ + c];
    const float invM = 1.0f / (float)M_TOT;
    float ms   = su * invM;
    float var  = fmaf(-ms, ms, s2 * invM);
    float mean = SHIFT_ + ms;
    float scale = rsqrtf(var + BN_EPS) * gamma[c];
    float bias  = beta[c] - mean * scale;
    f32x4 v = ((const f32x4*)y)[i4];
    v.x = fmaf(v.x, scale, bias);
    v.y = fmaf(v.y, scale, bias);
    v.z = fmaf(v.z, scale, bias);
    v.w = fmaf(v.w, scale, bias);
    ((f32x4*)y)[i4] = v;
}

extern "C" void kernel_launch(void* const* d_in, const int* in_sizes, int n_in,
                              void* d_out, int out_size, void* d_ws, size_t ws_size,
                              hipStream_t stream) {
    const float* x     = (const float*)d_in[0];
    const float* w     = (const float*)d_in[1];
    const float* gamma = (const float*)d_in[2];
    const float* beta  = (const float*)d_in[3];
    float* y = (float*)d_out;

    char* ws = (char*)d_ws;
    unsigned short* xp    = (unsigned short*)(ws);
    float*          s     = (float*)(ws + S_OFF);
    float*          stats = (float*)(ws + ST_OFF);
    unsigned short* wp    = (unsigned short*)(ws + WP_OFF);

    init_ws<<<(ZERO_F4 + 255) / 256, 256, 0, stream>>>((float*)ws);
    pack_x<<<NB_ * 28, 256, 0, stream>>>(x, xp, s);
    pack_w<<<1152, 256, 0, stream>>>(w, wp);
    econv<<<784, 256, 0, stream>>>(xp, wp, s, y, stats);
    bn_apply<<<(NB_ * CO_ * NPIX / 4 + 255) / 256, 256, 0, stream>>>(y, stats, gamma, beta);
}

// Round 13
// 64.694 us; speedup vs baseline: 1.6719x; 1.6719x over previous
//
#include <hip/hip_runtime.h>

// EuclidConv + BatchNorm (training stats), fp32 in/out.
// y = 2*conv(x,w) + t1 (+t2 cancels in BN).  bf16 MFMA implicit GEMM:
//   M=25088 pixels, N=256 chans, K=9 taps*128 ci.
// Round 13: half-ci slab (38.4KB) staged twice -> 4 blocks/CU (16 waves/CU)
// for pipe overlap. Same total LDS/L2/MFMA work as r9; only residency changes.
// K-loop barrier-free within each ci-half; r12-verified two-pass epilogue.

typedef short  bf16x8 __attribute__((ext_vector_type(8)));
typedef float  f32x4  __attribute__((ext_vector_type(4)));

#define NPIX   784
#define CI_    128
#define CO_    256
#define NB_    32
#define M_     25088
#define SHIFT_ 1152.0f
#define BN_EPS 1e-5f
#define M_TOT  25088

// ws layout (bytes): xp [32][30][30][128] bf16 = 7,372,800 ; s [32][30][30] f32 ;
// stats [2][256] f32 ; wp [36][16][4][16][8] bf16 = 589,824 (round-2 layout)
#define S_OFF   7372800
#define ST_OFF  7488000
#define WP_OFF  7490048
#define ZERO_F4 468128            // (ST_OFF + 2048) / 16 : zeroes xp + s + stats

#define HSLAB_CHUNKS 2400         // 10 rows * 30 px * 8 chunks (64 ci half)

__device__ __forceinline__ unsigned short f2bf(float f) {
    unsigned int u = __float_as_uint(f);
    unsigned int r = (u + 0x7FFFu + ((u >> 16) & 1u)) >> 16;
    return (unsigned short)r;
}

__device__ __forceinline__ void gload_lds16(const void* gsrc, void* ldst) {
    __builtin_amdgcn_global_load_lds(
        (const __attribute__((address_space(1))) void*)gsrc,
        (__attribute__((address_space(3))) void*)ldst, 16, 0, 0);
}

__global__ __launch_bounds__(256) void init_ws(float* ws) {
    int i = blockIdx.x * 256 + threadIdx.x;
    if (i < ZERO_F4) ((f32x4*)ws)[i] = (f32x4){0.f, 0.f, 0.f, 0.f};
}

// ---- pack x: NCHW f32 -> padded NHWC bf16, plus s = sum_ci x^2 (round-2) ----
__global__ __launch_bounds__(256) void pack_x(const float* __restrict__ x,
                                              unsigned short* __restrict__ xp,
                                              float* __restrict__ s) {
    const int n = blockIdx.x / 28, h = blockIdx.x % 28, tid = threadIdx.x;
    __shared__ float xs[128][29];
    __shared__ float part[8][28];

    #pragma unroll
    for (int i = 0; i < 14; ++i) {
        int e = tid + i * 256;
        int ci = e / 28, w = e - ci * 28;
        xs[ci][w] = x[(size_t)(n * 128 + ci) * 784 + h * 28 + w];
    }
    __syncthreads();
    #pragma unroll
    for (int i = 0; i < 14; ++i) {
        int e = tid + i * 256;
        int w = e >> 7, ci = e & 127;
        xp[((size_t)(n * 30 + h + 1) * 30 + (w + 1)) * 128 + ci] = f2bf(xs[ci][w]);
    }
    if (tid < 224) {
        int grp = tid / 28, w = tid - grp * 28;
        float a = 0.f;
        #pragma unroll
        for (int ci = grp * 16; ci < grp * 16 + 16; ++ci) a = fmaf(xs[ci][w], xs[ci][w], a);
        part[grp][w] = a;
    }
    __syncthreads();
    if (tid < 28) {
        float a = 0.f;
        #pragma unroll
        for (int g = 0; g < 8; ++g) a += part[g][tid];
        s[n * 900 + (h + 1) * 30 + (tid + 1)] = a;
    }
}

// ---- pack w (round-2 verified): wp[kblk(36)][ng(16)][kb(4)][cc(16)][k8(8)] ----
__global__ __launch_bounds__(256) void pack_w(const float* __restrict__ w,
                                              unsigned short* __restrict__ wp) {
    int o = blockIdx.x * 256 + threadIdx.x;      // < 294912
    int k8   = o & 7;
    int cc   = (o >> 3) & 15;
    int kb   = (o >> 7) & 3;
    int ng   = (o >> 9) & 15;
    int kblk = o >> 13;                          // 0..35
    int tap  = kblk >> 2;
    int ci   = (kblk & 3) * 32 + kb * 8 + k8;
    int co   = ng * 16 + cc;
    wp[o] = f2bf(w[(size_t)(co * 128 + ci) * 9 + tap]);
}

// ---- MFMA implicit GEMM: BM=128, BN=64, 4 waves (2x2 of 64x32) ----
// Half-ci slab staged twice; barrier-free inner loops; 4 blocks/CU.
__global__ __launch_bounds__(256, 4) void econv(
        const unsigned short* __restrict__ xp, const unsigned short* __restrict__ wp,
        const float* __restrict__ s, float* __restrict__ y, float* __restrict__ stats) {
    __shared__ unsigned short slab[HSLAB_CHUNKS * 8];   // 38,400 B
    __shared__ float t1s[128];

    const int tid = threadIdx.x;
    // XCD-aware bijective swizzle (784 = 8*98)
    int bid = blockIdx.x;
    int swz = (bid & 7) * 98 + (bid >> 3);
    const int nb = swz & 3;
    const int mb = swz >> 2;
    const int gblock = mb * 128;
    const int nblock = nb * 64;
    const int ng0 = nb * 4;

    const int n0  = gblock / 784;
    const int p0  = gblock - n0 * 784;
    const int GR0 = n0 * 30 + p0 / 28;
    const unsigned short* slabg = xp + (size_t)GR0 * 30 * 128;

    // t1 = 3x3 box of padded per-pixel sum of x^2
    if (tid < 128) {
        int g = gblock + tid; int n = g / 784, p = g - n * 784;
        int h = p / 28, wq = p - h * 28;
        const float* sb = s + n * 900 + h * 30 + wq;
        t1s[tid] = (sb[0] + sb[1] + sb[2]) + (sb[30] + sb[31] + sb[32]) + (sb[60] + sb[61] + sb[62]);
    }

    const int lane = tid & 63;
    const int wid  = tid >> 6;
    const int wm = wid >> 1, wn = wid & 1;
    const int l15 = lane & 15, l16 = lane >> 4;

    // per-lane slab pixel index (3x3 window top-left) for each fm row
    int Pp[4];
    #pragma unroll
    for (int fm = 0; fm < 4; ++fm) {
        int g = gblock + wm * 64 + fm * 16 + l15;
        int n = g / 784, p = g - n * 784;
        int h = p / 28, c = p - h * 28;
        Pp[fm] = (n * 30 + h - GR0) * 30 + c;
    }
    // per-lane B base: each wave's frag read is 1KB contiguous
    const unsigned short* wpl = wp + (size_t)((ng0 + wn * 2) * 64 + l16 * 16 + l15) * 8;

    f32x4 acc[4][2];
    #pragma unroll
    for (int a_ = 0; a_ < 4; ++a_)
        #pragma unroll
        for (int b_ = 0; b_ < 2; ++b_) acc[a_][b_] = (f32x4){0.f, 0.f, 0.f, 0.f};

    #pragma unroll 1
    for (int cihalf = 0; cihalf < 2; ++cihalf) {
        if (cihalf) __syncthreads();   // all waves done reading previous half
        // stage half-ci slab: pixel Q, slot sl (0..7) holds source chunk sl^(Q&7)
        #pragma unroll
        for (int i = 0; i < 10; ++i) {
            int sc = tid + i * 256;
            if (sc < HSLAB_CHUNKS) {
                int Q = sc >> 3, sl = sc & 7;
                int c = sl ^ (Q & 7);
                gload_lds16(slabg + (size_t)(Q * 16 + cihalf * 8 + c) * 8, &slab[sc * 8]);
            }
        }
        __syncthreads();   // slab half ready (vmcnt drained by barrier)

        #pragma unroll
        for (int tap = 0; tap < 9; ++tap) {
            const int toff = (tap / 3) * 30 + (tap % 3);
            bf16x8 aF[2][4], bF[2][2];
            #pragma unroll
            for (int kq = 0; kq < 2; ++kq) {
                #pragma unroll
                for (int fm = 0; fm < 4; ++fm) {
                    int P2 = Pp[fm] + toff;
                    int sl = (kq * 4 + l16) ^ (P2 & 7);
                    aF[kq][fm] = *(const bf16x8*)&slab[(P2 * 8 + sl) * 8];
                }
                const int K16 = (tap * 4 + cihalf * 2 + kq) * 16;
                #pragma unroll
                for (int fn = 0; fn < 2; ++fn)
                    bF[kq][fn] = *(const bf16x8*)&wpl[(size_t)(K16 + fn) * 512];
            }
            #pragma unroll
            for (int kq = 0; kq < 2; ++kq)
                #pragma unroll
                for (int fm = 0; fm < 4; ++fm)
                    #pragma unroll
                    for (int fn = 0; fn < 2; ++fn)
                        acc[fm][fn] = __builtin_amdgcn_mfma_f32_16x16x32_bf16(
                            aF[kq][fm], bF[kq][fn], acc[fm][fn], 0, 0, 0);
        }
    }

    // ---- epilogue: two-pass coalesced store via 32x132 LDS transpose (r12) ----
    float* ldsT = (float*)slab;   // 16,896 B <= 38,400
    float sSum[2] = {0.f, 0.f}, sSq[2] = {0.f, 0.f};
    #pragma unroll 1
    for (int pass = 0; pass < 2; ++pass) {
        __syncthreads();
        if (wn == pass) {
            #pragma unroll
            for (int fm = 0; fm < 4; ++fm) {
                #pragma unroll
                for (int j = 0; j < 4; ++j) {
                    int r = wm * 64 + fm * 16 + l16 * 4 + j;
                    float t1v = t1s[r];
                    #pragma unroll
                    for (int fn = 0; fn < 2; ++fn) {
                        float v = fmaf(2.f, acc[fm][fn][j], t1v);
                        ldsT[(fn * 16 + l15) * 132 + r] = v;
                        float d = v - SHIFT_;
                        sSum[fn] += d;
                        sSq[fn] = fmaf(d, d, sSq[fn]);
                    }
                }
            }
        }
        __syncthreads();
        #pragma unroll
        for (int i = 0; i < 4; ++i) {
            int idx = tid + i * 256;       // 0..1023
            int co  = idx >> 5;            // 0..31
            int r   = (idx & 31) * 4;      // block-local pixel, mult of 4
            int g   = gblock + r;
            int n = g / 784, p = g - n * 784;   // crossings at mult of 16: never split
            f32x4 v = *(const f32x4*)&ldsT[co * 132 + r];
            *(f32x4*)&y[(size_t)n * 200704 + (size_t)(nblock + pass * 32 + co) * 784 + p] = v;
        }
    }

    #pragma unroll
    for (int fn = 0; fn < 2; ++fn) {
        float a = sSum[fn], b2 = sSq[fn];
        a  += __shfl_xor(a, 16);  a  += __shfl_xor(a, 32);
        b2 += __shfl_xor(b2, 16); b2 += __shfl_xor(b2, 32);
        if (l16 == 0) {
            int co = nblock + wn * 32 + fn * 16 + l15;
            atomicAdd(&stats[co], a);
            atomicAdd(&stats[256 + co], b2);
        }
    }
}

__global__ __launch_bounds__(256) void bn_apply(
        float* __restrict__ y, const float* __restrict__ stats,
        const float* __restrict__ gamma, const float* __restrict__ beta) {
    const int TOTAL4 = NB_ * CO_ * NPIX / 4;
    int i4 = blockIdx.x * 256 + threadIdx.x;
    if (i4 >= TOTAL4) return;
    int c = (i4 / (NPIX / 4)) & (CO_ - 1);
    float su = stats[c];
    float s2 = stats[CO_ + c];
    const float invM = 1.0f / (float)M_TOT;
    float ms   = su * invM;
    float var  = fmaf(-ms, ms, s2 * invM);
    float mean = SHIFT_ + ms;
    float scale = rsqrtf(var + BN_EPS) * gamma[c];
    float bias  = beta[c] - mean * scale;
    f32x4 v = ((const f32x4*)y)[i4];
    v.x = fmaf(v.x, scale, bias);
    v.y = fmaf(v.y, scale, bias);
    v.z = fmaf(v.z, scale, bias);
    v.w = fmaf(v.w, scale, bias);
    ((f32x4*)y)[i4] = v;
}

extern "C" void kernel_launch(void* const* d_in, const int* in_sizes, int n_in,
                              void* d_out, int out_size, void* d_ws, size_t ws_size,
                              hipStream_t stream) {
    const float* x     = (const float*)d_in[0];
    const float* w     = (const float*)d_in[1];
    const float* gamma = (const float*)d_in[2];
    const float* beta  = (const float*)d_in[3];
    float* y = (float*)d_out;

    char* ws = (char*)d_ws;
    unsigned short* xp    = (unsigned short*)(ws);
    float*          s     = (float*)(ws + S_OFF);
    float*          stats = (float*)(ws + ST_OFF);
    unsigned short* wp    = (unsigned short*)(ws + WP_OFF);

    init_ws<<<(ZERO_F4 + 255) / 256, 256, 0, stream>>>((float*)ws);
    pack_x<<<NB_ * 28, 256, 0, stream>>>(x, xp, s);
    pack_w<<<1152, 256, 0, stream>>>(w, wp);
    econv<<<784, 256, 0, stream>>>(xp, wp, s, y, stats);
    bn_apply<<<(NB_ * CO_ * NPIX / 4 + 255) / 256, 256, 0, stream>>>(y, stats, gamma, beta);
}

// Round 14
// 50.507 us; speedup vs baseline: 2.1415x; 1.2809x over previous
//
#include <hip/hip_runtime.h>

// EuclidConv + BatchNorm (training stats), fp32 in/out.
// y = 2*conv(x,w) + t1 (+t2 cancels in BN).  bf16 MFMA implicit GEMM:
//   M=25088 pixels, N=256 chans, K=9 taps*128 ci.
// Round 14: r9 (best, 55.6us) with overhead trims: init_ws deleted —
// border-only zeroing (xp/s borders + stats) folded into pack_w at disjoint
// addresses; 4 launches instead of 5. econv/bn_apply byte-identical to r9.

typedef short  bf16x8 __attribute__((ext_vector_type(8)));
typedef float  f32x4  __attribute__((ext_vector_type(4)));

#define NPIX   784
#define CI_    128
#define CO_    256
#define NB_    32
#define M_     25088
#define SHIFT_ 1152.0f
#define BN_EPS 1e-5f
#define M_TOT  25088

// ws layout (bytes): xp [32][30][30][128] bf16 = 7,372,800 ; s [32][30][30] f32 ;
// stats [2][256] f32 ; wp [36][16][4][16][8] bf16 = 589,824 (round-2 layout)
#define S_OFF   7372800
#define ST_OFF  7488000
#define WP_OFF  7490048

#define SLAB_CHUNKS 4864          // 19*256; >= 10 rows * 30 * 16 = 4800

__device__ __forceinline__ unsigned short f2bf(float f) {
    unsigned int u = __float_as_uint(f);
    unsigned int r = (u + 0x7FFFu + ((u >> 16) & 1u)) >> 16;
    return (unsigned short)r;
}

__device__ __forceinline__ void gload_lds16(const void* gsrc, void* ldst) {
    __builtin_amdgcn_global_load_lds(
        (const __attribute__((address_space(1))) void*)gsrc,
        (__attribute__((address_space(3))) void*)ldst, 16, 0, 0);
}

// ---- pack x: NCHW f32 -> padded NHWC bf16, plus s = sum_ci x^2 (round-2) ----
__global__ __launch_bounds__(256) void pack_x(const float* __restrict__ x,
                                              unsigned short* __restrict__ xp,
                                              float* __restrict__ s) {
    const int n = blockIdx.x / 28, h = blockIdx.x % 28, tid = threadIdx.x;
    __shared__ float xs[128][29];
    __shared__ float part[8][28];

    #pragma unroll
    for (int i = 0; i < 14; ++i) {
        int e = tid + i * 256;
        int ci = e / 28, w = e - ci * 28;
        xs[ci][w] = x[(size_t)(n * 128 + ci) * 784 + h * 28 + w];
    }
    __syncthreads();
    #pragma unroll
    for (int i = 0; i < 14; ++i) {
        int e = tid + i * 256;
        int w = e >> 7, ci = e & 127;
        xp[((size_t)(n * 30 + h + 1) * 30 + (w + 1)) * 128 + ci] = f2bf(xs[ci][w]);
    }
    if (tid < 224) {
        int grp = tid / 28, w = tid - grp * 28;
        float a = 0.f;
        #pragma unroll
        for (int ci = grp * 16; ci < grp * 16 + 16; ++ci) a = fmaf(xs[ci][w], xs[ci][w], a);
        part[grp][w] = a;
    }
    __syncthreads();
    if (tid < 28) {
        float a = 0.f;
        #pragma unroll
        for (int g = 0; g < 8; ++g) a += part[g][tid];
        s[n * 900 + (h + 1) * 30 + (tid + 1)] = a;
    }
}

// border pixel bp (0..115 within image): padded (row,col) of the zero ring
__device__ __forceinline__ int border_px(int b) {
    if (b < 30)  return 0 * 30 + b;              // top row, cols 0..29
    if (b < 60)  return 29 * 30 + (b - 30);      // bottom row
    if (b < 88)  return (1 + (b - 60)) * 30 + 0; // left col, rows 1..28
    return (1 + (b - 88)) * 30 + 29;             // right col
}

// ---- pack w (round-2 verified layout) + border zeroing + stats zeroing ----
__global__ __launch_bounds__(256) void pack_w(const float* __restrict__ w,
                                              unsigned short* __restrict__ wp,
                                              unsigned short* __restrict__ xp,
                                              float* __restrict__ s,
                                              float* __restrict__ stats) {
    int o = blockIdx.x * 256 + threadIdx.x;      // < 294912
    {   // weight repack (unchanged)
        int k8   = o & 7;
        int cc   = (o >> 3) & 15;
        int kb   = (o >> 7) & 3;
        int ng   = (o >> 9) & 15;
        int kblk = o >> 13;                      // 0..35
        int tap  = kblk >> 2;
        int ci   = (kblk & 3) * 32 + kb * 8 + k8;
        int co   = ng * 16 + cc;
        wp[o] = f2bf(w[(size_t)(co * 128 + ci) * 9 + tap]);
    }
    // xp border zeroing: 3712 border pixels x 128 ci, as 16B chunks (x16)
    if (o < 3712 * 16) {
        int bp = o >> 4, part = o & 15;
        int n = bp / 116, b = bp - n * 116;
        size_t px = (size_t)n * 900 + border_px(b);
        *(f32x4*)&xp[px * 128 + part * 8] = (f32x4){0.f, 0.f, 0.f, 0.f};
    } else if (o < 3712 * 16 + 3712) {           // s border zeroing
        int bp = o - 3712 * 16;
        int n = bp / 116, b = bp - n * 116;
        s[n * 900 + border_px(b)] = 0.f;
    } else if (o < 3712 * 16 + 3712 + 512) {     // stats zeroing
        stats[o - (3712 * 16 + 3712)] = 0.f;
    }
}

// ---- MFMA implicit GEMM: BM=128, BN=64, 4 waves (2x2 of 64x32) ----
// A-slab resident in LDS (staged once, 10 rows); barrier-free K-loop with
// 1-step register prefetch; coalesced LDS-transpose epilogue. (r9 verified)
__global__ __launch_bounds__(256, 2) void econv(
        const unsigned short* __restrict__ xp, const unsigned short* __restrict__ wp,
        const float* __restrict__ s, float* __restrict__ y, float* __restrict__ stats) {
    __shared__ unsigned short slab[SLAB_CHUNKS * 8];   // 77,824 B: 10 padded rows
    __shared__ float t1s[128];

    const int tid = threadIdx.x;
    // XCD-aware bijective swizzle (784 = 8*98)
    int bid = blockIdx.x;
    int swz = (bid & 7) * 98 + (bid >> 3);
    const int nb = swz & 3;
    const int mb = swz >> 2;
    const int gblock = mb * 128;
    const int nblock = nb * 64;
    const int ng0 = nb * 4;

    // slab covers global padded rows GR0..GR0+9 (crossing blocks need 10)
    const int n0  = gblock / 784;
    const int p0  = gblock - n0 * 784;
    const int GR0 = n0 * 30 + p0 / 28;
    const unsigned short* slabg = xp + (size_t)GR0 * 30 * 128;

    // stage slab once: linear LDS dest, source pre-swizzled.
    // slot sl of pixel Q holds source chunk c = (sl&8)|((sl&7)^(Q&7)).
    #pragma unroll
    for (int i = 0; i < 19; ++i) {
        int sc = tid + i * 256;
        int Q = sc >> 4, sl = sc & 15;
        int c = (sl & 8) | ((sl & 7) ^ (Q & 7));
        gload_lds16(slabg + (size_t)(Q * 16 + c) * 8, &slab[sc * 8]);
    }

    // t1 = 3x3 box of padded per-pixel sum of x^2
    if (tid < 128) {
        int g = gblock + tid; int n = g / 784, p = g - n * 784;
        int h = p / 28, wq = p - h * 28;
        const float* sb = s + n * 900 + h * 30 + wq;
        t1s[tid] = (sb[0] + sb[1] + sb[2]) + (sb[30] + sb[31] + sb[32]) + (sb[60] + sb[61] + sb[62]);
    }

    const int lane = tid & 63;
    const int wid  = tid >> 6;
    const int wm = wid >> 1, wn = wid & 1;
    const int l15 = lane & 15, l16 = lane >> 4;

    // per-lane slab pixel index (3x3 window top-left) for each fm row
    int Pp[4];
    #pragma unroll
    for (int fm = 0; fm < 4; ++fm) {
        int g = gblock + wm * 64 + fm * 16 + l15;
        int n = g / 784, p = g - n * 784;
        int h = p / 28, c = p - h * 28;
        Pp[fm] = (n * 30 + h - GR0) * 30 + c;
    }
    // per-lane B base: each wave's frag read is 1KB contiguous
    const unsigned short* wpl = wp + (size_t)((ng0 + wn * 2) * 64 + l16 * 16 + l15) * 8;

    f32x4 acc[4][2];
    #pragma unroll
    for (int a_ = 0; a_ < 4; ++a_)
        #pragma unroll
        for (int b_ = 0; b_ < 2; ++b_) acc[a_][b_] = (f32x4){0.f, 0.f, 0.f, 0.f};

    __syncthreads();   // slab + t1s ready; no barriers in K-loop

#define LOADK(ks, A, B) {                                                    \
    const int tap_ = (ks) >> 1, half_ = (ks) & 1;                            \
    const int toff_ = (tap_ / 3) * 30 + (tap_ % 3);                          \
    _Pragma("unroll") for (int q_ = 0; q_ < 2; ++q_) {                       \
        _Pragma("unroll") for (int fm_ = 0; fm_ < 4; ++fm_) {                \
            int P2_ = Pp[fm_] + toff_;                                       \
            int sl_ = half_ * 8 + ((q_ * 4 + l16) ^ (P2_ & 7));              \
            A[q_][fm_] = *(const bf16x8*)&slab[(P2_ * 16 + sl_) * 8];        \
        }                                                                    \
        const int K16_ = (tap_ * 4 + half_ * 2 + q_) * 16;                   \
        _Pragma("unroll") for (int fn_ = 0; fn_ < 2; ++fn_)                  \
            B[q_][fn_] = *(const bf16x8*)&wpl[(size_t)(K16_ + fn_) * 512];   \
    }                                                                        \
}

    bf16x8 aP[2][2][4], bP[2][2][2];
    LOADK(0, aP[0], bP[0]);
    #pragma unroll
    for (int ks = 0; ks < 18; ++ks) {
        const int cur = ks & 1;          // compile-time after unroll
        if (ks < 17) LOADK(ks + 1, aP[cur ^ 1], bP[cur ^ 1]);
        #pragma unroll
        for (int q = 0; q < 2; ++q)
            #pragma unroll
            for (int fm = 0; fm < 4; ++fm)
                #pragma unroll
                for (int fn = 0; fn < 2; ++fn)
                    acc[fm][fn] = __builtin_amdgcn_mfma_f32_16x16x32_bf16(
                        aP[cur][q][fm], bP[cur][q][fn], acc[fm][fn], 0, 0, 0);
    }
#undef LOADK

    // ---- epilogue: coalesced via LDS transpose (slab reused) ----
    __syncthreads();   // all waves finished reading slab
    float* ldsT = (float*)slab;   // [64 co][132] floats = 33,792 B

    float sSum[2] = {0.f, 0.f}, sSq[2] = {0.f, 0.f};
    #pragma unroll
    for (int fm = 0; fm < 4; ++fm) {
        #pragma unroll
        for (int j = 0; j < 4; ++j) {
            int r = wm * 64 + fm * 16 + l16 * 4 + j;
            float t1v = t1s[r];
            #pragma unroll
            for (int fn = 0; fn < 2; ++fn) {
                float v = fmaf(2.f, acc[fm][fn][j], t1v);
                ldsT[(wn * 32 + fn * 16 + l15) * 132 + r] = v;
                float d = v - SHIFT_;
                sSum[fn] += d;
                sSq[fn] = fmaf(d, d, sSq[fn]);
            }
        }
    }
    __syncthreads();
    // coalesced store: thread reads f32x4 per (co, 4 consecutive pixels)
    #pragma unroll
    for (int i = 0; i < 8; ++i) {
        int idx = tid + i * 256;       // 0..2047
        int co  = idx >> 5;            // 0..63
        int r   = (idx & 31) * 4;      // block-local pixel, mult of 4
        int g   = gblock + r;
        int n = g / 784, p = g - n * 784;   // crossings at mult of 16: never split
        f32x4 v = *(const f32x4*)&ldsT[co * 132 + r];
        *(f32x4*)&y[(size_t)n * 200704 + (size_t)(nblock + co) * 784 + p] = v;
    }

    #pragma unroll
    for (int fn = 0; fn < 2; ++fn) {
        float a = sSum[fn], b2 = sSq[fn];
        a  += __shfl_xor(a, 16);  a  += __shfl_xor(a, 32);
        b2 += __shfl_xor(b2, 16); b2 += __shfl_xor(b2, 32);
        if (l16 == 0) {
            int co = nblock + wn * 32 + fn * 16 + l15;
            atomicAdd(&stats[co], a);
            atomicAdd(&stats[256 + co], b2);
        }
    }
}

__global__ __launch_bounds__(256) void bn_apply(
        float* __restrict__ y, const float* __restrict__ stats,
        const float* __restrict__ gamma, const float* __restrict__ beta) {
    const int TOTAL4 = NB_ * CO_ * NPIX / 4;
    int i4 = blockIdx.x * 256 + threadIdx.x;
    if (i4 >= TOTAL4) return;
    int c = (i4 / (NPIX / 4)) & (CO_ - 1);
    float su = stats[c];
    float s2 = stats[CO_ + c];
    const float invM = 1.0f / (float)M_TOT;
    float ms   = su * invM;
    float var  = fmaf(-ms, ms, s2 * invM);
    float mean = SHIFT_ + ms;
    float scale = rsqrtf(var + BN_EPS) * gamma[c];
    float bias  = beta[c] - mean * scale;
    f32x4 v = ((const f32x4*)y)[i4];
    v.x = fmaf(v.x, scale, bias);
    v.y = fmaf(v.y, scale, bias);
    v.z = fmaf(v.z, scale, bias);
    v.w = fmaf(v.w, scale, bias);
    ((f32x4*)y)[i4] = v;
}

extern "C" void kernel_launch(void* const* d_in, const int* in_sizes, int n_in,
                              void* d_out, int out_size, void* d_ws, size_t ws_size,
                              hipStream_t stream) {
    const float* x     = (const float*)d_in[0];
    const float* w     = (const float*)d_in[1];
    const float* gamma = (const float*)d_in[2];
    const float* beta  = (const float*)d_in[3];
    float* y = (float*)d_out;

    char* ws = (char*)d_ws;
    unsigned short* xp    = (unsigned short*)(ws);
    float*          s     = (float*)(ws + S_OFF);
    float*          stats = (float*)(ws + ST_OFF);
    unsigned short* wp    = (unsigned short*)(ws + WP_OFF);

    pack_x<<<NB_ * 28, 256, 0, stream>>>(x, xp, s);
    pack_w<<<1152, 256, 0, stream>>>(w, wp, xp, s, stats);
    econv<<<784, 256, 0, stream>>>(xp, wp, s, y, stats);
    bn_apply<<<(NB_ * CO_ * NPIX / 4 + 255) / 256, 256, 0, stream>>>(y, stats, gamma, beta);
}

// Round 15
// 44.861 us; speedup vs baseline: 2.4111x; 1.1259x over previous
//
#include <hip/hip_runtime.h>

// EuclidConv + BatchNorm (training stats), fp32 in/out.
// y = 2*conv(x,w) + t1 (+t2 cancels in BN).  bf16 MFMA implicit GEMM:
//   M=25088 pixels, N=256 chans, K=9 taps*128 ci.
// Round 15: r14 base + (1) pack_x/pack_w merged into one pack_all launch
// (3 launches total), (2) T5 s_setprio(1/0) around econv's MFMA clusters
// (barrier-free K-loop -> phase-diverse waves, the regime where T5 pays).

typedef short  bf16x8 __attribute__((ext_vector_type(8)));
typedef float  f32x4  __attribute__((ext_vector_type(4)));

#define NPIX   784
#define CI_    128
#define CO_    256
#define NB_    32
#define M_     25088
#define SHIFT_ 1152.0f
#define BN_EPS 1e-5f
#define M_TOT  25088

// ws layout (bytes): xp [32][30][30][128] bf16 = 7,372,800 ; s [32][30][30] f32 ;
// stats [2][256] f32 ; wp [36][16][4][16][8] bf16 = 589,824 (round-2 layout)
#define S_OFF   7372800
#define ST_OFF  7488000
#define WP_OFF  7490048

#define SLAB_CHUNKS 4864          // 19*256; >= 10 rows * 30 * 16 = 4800

__device__ __forceinline__ unsigned short f2bf(float f) {
    unsigned int u = __float_as_uint(f);
    unsigned int r = (u + 0x7FFFu + ((u >> 16) & 1u)) >> 16;
    return (unsigned short)r;
}

__device__ __forceinline__ void gload_lds16(const void* gsrc, void* ldst) {
    __builtin_amdgcn_global_load_lds(
        (const __attribute__((address_space(1))) void*)gsrc,
        (__attribute__((address_space(3))) void*)ldst, 16, 0, 0);
}

// border pixel bp (0..115 within image): padded (row,col) of the zero ring
__device__ __forceinline__ int border_px(int b) {
    if (b < 30)  return 0 * 30 + b;              // top row, cols 0..29
    if (b < 60)  return 29 * 30 + (b - 30);      // bottom row
    if (b < 88)  return (1 + (b - 60)) * 30 + 0; // left col, rows 1..28
    return (1 + (b - 88)) * 30 + 29;             // right col
}

// ---- merged pack: blocks 0..895 pack_x; blocks 896..2047 pack_w + zeroing ----
__global__ __launch_bounds__(256) void pack_all(
        const float* __restrict__ x, unsigned short* __restrict__ xp,
        float* __restrict__ s, const float* __restrict__ w,
        unsigned short* __restrict__ wp, float* __restrict__ stats) {
    const int tid = threadIdx.x;

    if (blockIdx.x >= 896) {
        // ---- pack_w path (r14-verified) ----
        int o = (blockIdx.x - 896) * 256 + tid;  // < 294912
        {   // weight repack: wp[kblk(36)][ng(16)][kb(4)][cc(16)][k8(8)]
            int k8   = o & 7;
            int cc   = (o >> 3) & 15;
            int kb   = (o >> 7) & 3;
            int ng   = (o >> 9) & 15;
            int kblk = o >> 13;                  // 0..35
            int tap  = kblk >> 2;
            int ci   = (kblk & 3) * 32 + kb * 8 + k8;
            int co   = ng * 16 + cc;
            wp[o] = f2bf(w[(size_t)(co * 128 + ci) * 9 + tap]);
        }
        if (o < 3712 * 16) {                     // xp border zeroing (16B chunks)
            int bp = o >> 4, part = o & 15;
            int n = bp / 116, b = bp - n * 116;
            size_t px = (size_t)n * 900 + border_px(b);
            *(f32x4*)&xp[px * 128 + part * 8] = (f32x4){0.f, 0.f, 0.f, 0.f};
        } else if (o < 3712 * 16 + 3712) {       // s border zeroing
            int bp = o - 3712 * 16;
            int n = bp / 116, b = bp - n * 116;
            s[n * 900 + border_px(b)] = 0.f;
        } else if (o < 3712 * 16 + 3712 + 512) { // stats zeroing
            stats[o - (3712 * 16 + 3712)] = 0.f;
        }
        return;
    }

    // ---- pack_x path (r14-verified) ----
    const int n = blockIdx.x / 28, h = blockIdx.x % 28;
    __shared__ float xs[128][29];
    __shared__ float part[8][28];

    #pragma unroll
    for (int i = 0; i < 14; ++i) {
        int e = tid + i * 256;
        int ci = e / 28, ww = e - ci * 28;
        xs[ci][ww] = x[(size_t)(n * 128 + ci) * 784 + h * 28 + ww];
    }
    __syncthreads();
    #pragma unroll
    for (int i = 0; i < 14; ++i) {
        int e = tid + i * 256;
        int ww = e >> 7, ci = e & 127;
        xp[((size_t)(n * 30 + h + 1) * 30 + (ww + 1)) * 128 + ci] = f2bf(xs[ci][ww]);
    }
    if (tid < 224) {
        int grp = tid / 28, ww = tid - grp * 28;
        float a = 0.f;
        #pragma unroll
        for (int ci = grp * 16; ci < grp * 16 + 16; ++ci) a = fmaf(xs[ci][ww], xs[ci][ww], a);
        part[grp][ww] = a;
    }
    __syncthreads();
    if (tid < 28) {
        float a = 0.f;
        #pragma unroll
        for (int g = 0; g < 8; ++g) a += part[g][tid];
        s[n * 900 + (h + 1) * 30 + (tid + 1)] = a;
    }
}

// ---- MFMA implicit GEMM: BM=128, BN=64, 4 waves (2x2 of 64x32) ----
// A-slab resident in LDS (staged once, 10 rows); barrier-free K-loop with
// 1-step register prefetch + setprio around MFMA; coalesced epilogue.
__global__ __launch_bounds__(256, 2) void econv(
        const unsigned short* __restrict__ xp, const unsigned short* __restrict__ wp,
        const float* __restrict__ s, float* __restrict__ y, float* __restrict__ stats) {
    __shared__ unsigned short slab[SLAB_CHUNKS * 8];   // 77,824 B: 10 padded rows
    __shared__ float t1s[128];

    const int tid = threadIdx.x;
    // XCD-aware bijective swizzle (784 = 8*98)
    int bid = blockIdx.x;
    int swz = (bid & 7) * 98 + (bid >> 3);
    const int nb = swz & 3;
    const int mb = swz >> 2;
    const int gblock = mb * 128;
    const int nblock = nb * 64;
    const int ng0 = nb * 4;

    // slab covers global padded rows GR0..GR0+9 (crossing blocks need 10)
    const int n0  = gblock / 784;
    const int p0  = gblock - n0 * 784;
    const int GR0 = n0 * 30 + p0 / 28;
    const unsigned short* slabg = xp + (size_t)GR0 * 30 * 128;

    // stage slab once: linear LDS dest, source pre-swizzled.
    // slot sl of pixel Q holds source chunk c = (sl&8)|((sl&7)^(Q&7)).
    #pragma unroll
    for (int i = 0; i < 19; ++i) {
        int sc = tid + i * 256;
        int Q = sc >> 4, sl = sc & 15;
        int c = (sl & 8) | ((sl & 7) ^ (Q & 7));
        gload_lds16(slabg + (size_t)(Q * 16 + c) * 8, &slab[sc * 8]);
    }

    // t1 = 3x3 box of padded per-pixel sum of x^2
    if (tid < 128) {
        int g = gblock + tid; int n = g / 784, p = g - n * 784;
        int h = p / 28, wq = p - h * 28;
        const float* sb = s + n * 900 + h * 30 + wq;
        t1s[tid] = (sb[0] + sb[1] + sb[2]) + (sb[30] + sb[31] + sb[32]) + (sb[60] + sb[61] + sb[62]);
    }

    const int lane = tid & 63;
    const int wid  = tid >> 6;
    const int wm = wid >> 1, wn = wid & 1;
    const int l15 = lane & 15, l16 = lane >> 4;

    // per-lane slab pixel index (3x3 window top-left) for each fm row
    int Pp[4];
    #pragma unroll
    for (int fm = 0; fm < 4; ++fm) {
        int g = gblock + wm * 64 + fm * 16 + l15;
        int n = g / 784, p = g - n * 784;
        int h = p / 28, c = p - h * 28;
        Pp[fm] = (n * 30 + h - GR0) * 30 + c;
    }
    // per-lane B base: each wave's frag read is 1KB contiguous
    const unsigned short* wpl = wp + (size_t)((ng0 + wn * 2) * 64 + l16 * 16 + l15) * 8;

    f32x4 acc[4][2];
    #pragma unroll
    for (int a_ = 0; a_ < 4; ++a_)
        #pragma unroll
        for (int b_ = 0; b_ < 2; ++b_) acc[a_][b_] = (f32x4){0.f, 0.f, 0.f, 0.f};

    __syncthreads();   // slab + t1s ready; no barriers in K-loop

#define LOADK(ks, A, B) {                                                    \
    const int tap_ = (ks) >> 1, half_ = (ks) & 1;                            \
    const int toff_ = (tap_ / 3) * 30 + (tap_ % 3);                          \
    _Pragma("unroll") for (int q_ = 0; q_ < 2; ++q_) {                       \
        _Pragma("unroll") for (int fm_ = 0; fm_ < 4; ++fm_) {                \
            int P2_ = Pp[fm_] + toff_;                                       \
            int sl_ = half_ * 8 + ((q_ * 4 + l16) ^ (P2_ & 7));              \
            A[q_][fm_] = *(const bf16x8*)&slab[(P2_ * 16 + sl_) * 8];        \
        }                                                                    \
        const int K16_ = (tap_ * 4 + half_ * 2 + q_) * 16;                   \
        _Pragma("unroll") for (int fn_ = 0; fn_ < 2; ++fn_)                  \
            B[q_][fn_] = *(const bf16x8*)&wpl[(size_t)(K16_ + fn_) * 512];   \
    }                                                                        \
}

    bf16x8 aP[2][2][4], bP[2][2][2];
    LOADK(0, aP[0], bP[0]);
    #pragma unroll
    for (int ks = 0; ks < 18; ++ks) {
        const int cur = ks & 1;          // compile-time after unroll
        if (ks < 17) LOADK(ks + 1, aP[cur ^ 1], bP[cur ^ 1]);
        __builtin_amdgcn_s_setprio(1);   // T5: favor MFMA-issuing wave
        #pragma unroll
        for (int q = 0; q < 2; ++q)
            #pragma unroll
            for (int fm = 0; fm < 4; ++fm)
                #pragma unroll
                for (int fn = 0; fn < 2; ++fn)
                    acc[fm][fn] = __builtin_amdgcn_mfma_f32_16x16x32_bf16(
                        aP[cur][q][fm], bP[cur][q][fn], acc[fm][fn], 0, 0, 0);
        __builtin_amdgcn_s_setprio(0);
    }
#undef LOADK

    // ---- epilogue: coalesced via LDS transpose (slab reused) ----
    __syncthreads();   // all waves finished reading slab
    float* ldsT = (float*)slab;   // [64 co][132] floats = 33,792 B

    float sSum[2] = {0.f, 0.f}, sSq[2] = {0.f, 0.f};
    #pragma unroll
    for (int fm = 0; fm < 4; ++fm) {
        #pragma unroll
        for (int j = 0; j < 4; ++j) {
            int r = wm * 64 + fm * 16 + l16 * 4 + j;
            float t1v = t1s[r];
            #pragma unroll
            for (int fn = 0; fn < 2; ++fn) {
                float v = fmaf(2.f, acc[fm][fn][j], t1v);
                ldsT[(wn * 32 + fn * 16 + l15) * 132 + r] = v;
                float d = v - SHIFT_;
                sSum[fn] += d;
                sSq[fn] = fmaf(d, d, sSq[fn]);
            }
        }
    }
    __syncthreads();
    // coalesced store: thread reads f32x4 per (co, 4 consecutive pixels)
    #pragma unroll
    for (int i = 0; i < 8; ++i) {
        int idx = tid + i * 256;       // 0..2047
        int co  = idx >> 5;            // 0..63
        int r   = (idx & 31) * 4;      // block-local pixel, mult of 4
        int g   = gblock + r;
        int n = g / 784, p = g - n * 784;   // crossings at mult of 16: never split
        f32x4 v = *(const f32x4*)&ldsT[co * 132 + r];
        *(f32x4*)&y[(size_t)n * 200704 + (size_t)(nblock + co) * 784 + p] = v;
    }

    #pragma unroll
    for (int fn = 0; fn < 2; ++fn) {
        float a = sSum[fn], b2 = sSq[fn];
        a  += __shfl_xor(a, 16);  a  += __shfl_xor(a, 32);
        b2 += __shfl_xor(b2, 16); b2 += __shfl_xor(b2, 32);
        if (l16 == 0) {
            int co = nblock + wn * 32 + fn * 16 + l15;
            atomicAdd(&stats[co], a);
            atomicAdd(&stats[256 + co], b2);
        }
    }
}

__global__ __launch_bounds__(256) void bn_apply(
        float* __restrict__ y, const float* __restrict__ stats,
        const float* __restrict__ gamma, const float* __restrict__ beta) {
    const int TOTAL4 = NB_ * CO_ * NPIX / 4;
    int i4 = blockIdx.x * 256 + threadIdx.x;
    if (i4 >= TOTAL4) return;
    int c = (i4 / (NPIX / 4)) & (CO_ - 1);
    float su = stats[c];
    float s2 = stats[CO_ + c];
    const float invM = 1.0f / (float)M_TOT;
    float ms   = su * invM;
    float var  = fmaf(-ms, ms, s2 * invM);
    float mean = SHIFT_ + ms;
    float scale = rsqrtf(var + BN_EPS) * gamma[c];
    float bias  = beta[c] - mean * scale;
    f32x4 v = ((const f32x4*)y)[i4];
    v.x = fmaf(v.x, scale, bias);
    v.y = fmaf(v.y, scale, bias);
    v.z = fmaf(v.z, scale, bias);
    v.w = fmaf(v.w, scale, bias);
    ((f32x4*)y)[i4] = v;
}

extern "C" void kernel_launch(void* const* d_in, const int* in_sizes, int n_in,
                              void* d_out, int out_size, void* d_ws, size_t ws_size,
                              hipStream_t stream) {
    const float* x     = (const float*)d_in[0];
    const float* w     = (const float*)d_in[1];
    const float* gamma = (const float*)d_in[2];
    const float* beta  = (const float*)d_in[3];
    float* y = (float*)d_out;

    char* ws = (char*)d_ws;
    unsigned short* xp    = (unsigned short*)(ws);
    float*          s     = (float*)(ws + S_OFF);
    float*          stats = (float*)(ws + ST_OFF);
    unsigned short* wp    = (unsigned short*)(ws + WP_OFF);

    pack_all<<<2048, 256, 0, stream>>>(x, xp, s, w, wp, stats);
    econv<<<784, 256, 0, stream>>>(xp, wp, s, y, stats);
    bn_apply<<<(NB_ * CO_ * NPIX / 4 + 255) / 256, 256, 0, stream>>>(y, stats, gamma, beta);
}

// Round 17
// 44.813 us; speedup vs baseline: 2.4136x; 1.0011x over previous
//
#include <hip/hip_runtime.h>

// EuclidConv + BatchNorm (training stats), fp32 in/out.
// y = 2*conv(x,w) + t1 (+t2 cancels in BN).  bf16 MFMA implicit GEMM:
//   M=25088 pixels, N=256 chans, K=9 taps*128 ci.
// Round 17: exact revert to r15 (verified best, 44.9us). r16's BM=112 variant
// passed first validation but failed graph-replay re-validation (latent
// schedule-dependent race, unexplained after full audit) -> discarded.

typedef short  bf16x8 __attribute__((ext_vector_type(8)));
typedef float  f32x4  __attribute__((ext_vector_type(4)));

#define NPIX   784
#define CI_    128
#define CO_    256
#define NB_    32
#define M_     25088
#define SHIFT_ 1152.0f
#define BN_EPS 1e-5f
#define M_TOT  25088

// ws layout (bytes): xp [32][30][30][128] bf16 = 7,372,800 ; s [32][30][30] f32 ;
// stats [2][256] f32 ; wp [36][16][4][16][8] bf16 = 589,824 (round-2 layout)
#define S_OFF   7372800
#define ST_OFF  7488000
#define WP_OFF  7490048

#define SLAB_CHUNKS 4864          // 19*256; >= 10 rows * 30 * 16 = 4800

__device__ __forceinline__ unsigned short f2bf(float f) {
    unsigned int u = __float_as_uint(f);
    unsigned int r = (u + 0x7FFFu + ((u >> 16) & 1u)) >> 16;
    return (unsigned short)r;
}

__device__ __forceinline__ void gload_lds16(const void* gsrc, void* ldst) {
    __builtin_amdgcn_global_load_lds(
        (const __attribute__((address_space(1))) void*)gsrc,
        (__attribute__((address_space(3))) void*)ldst, 16, 0, 0);
}

// border pixel bp (0..115 within image): padded (row,col) of the zero ring
__device__ __forceinline__ int border_px(int b) {
    if (b < 30)  return 0 * 30 + b;              // top row, cols 0..29
    if (b < 60)  return 29 * 30 + (b - 30);      // bottom row
    if (b < 88)  return (1 + (b - 60)) * 30 + 0; // left col, rows 1..28
    return (1 + (b - 88)) * 30 + 29;             // right col
}

// ---- merged pack: blocks 0..895 pack_x; blocks 896..2047 pack_w + zeroing ----
__global__ __launch_bounds__(256) void pack_all(
        const float* __restrict__ x, unsigned short* __restrict__ xp,
        float* __restrict__ s, const float* __restrict__ w,
        unsigned short* __restrict__ wp, float* __restrict__ stats) {
    const int tid = threadIdx.x;

    if (blockIdx.x >= 896) {
        // ---- pack_w path (r14-verified) ----
        int o = (blockIdx.x - 896) * 256 + tid;  // < 294912
        {   // weight repack: wp[kblk(36)][ng(16)][kb(4)][cc(16)][k8(8)]
            int k8   = o & 7;
            int cc   = (o >> 3) & 15;
            int kb   = (o >> 7) & 3;
            int ng   = (o >> 9) & 15;
            int kblk = o >> 13;                  // 0..35
            int tap  = kblk >> 2;
            int ci   = (kblk & 3) * 32 + kb * 8 + k8;
            int co   = ng * 16 + cc;
            wp[o] = f2bf(w[(size_t)(co * 128 + ci) * 9 + tap]);
        }
        if (o < 3712 * 16) {                     // xp border zeroing (16B chunks)
            int bp = o >> 4, part = o & 15;
            int n = bp / 116, b = bp - n * 116;
            size_t px = (size_t)n * 900 + border_px(b);
            *(f32x4*)&xp[px * 128 + part * 8] = (f32x4){0.f, 0.f, 0.f, 0.f};
        } else if (o < 3712 * 16 + 3712) {       // s border zeroing
            int bp = o - 3712 * 16;
            int n = bp / 116, b = bp - n * 116;
            s[n * 900 + border_px(b)] = 0.f;
        } else if (o < 3712 * 16 + 3712 + 512) { // stats zeroing
            stats[o - (3712 * 16 + 3712)] = 0.f;
        }
        return;
    }

    // ---- pack_x path (r14-verified) ----
    const int n = blockIdx.x / 28, h = blockIdx.x % 28;
    __shared__ float xs[128][29];
    __shared__ float part[8][28];

    #pragma unroll
    for (int i = 0; i < 14; ++i) {
        int e = tid + i * 256;
        int ci = e / 28, ww = e - ci * 28;
        xs[ci][ww] = x[(size_t)(n * 128 + ci) * 784 + h * 28 + ww];
    }
    __syncthreads();
    #pragma unroll
    for (int i = 0; i < 14; ++i) {
        int e = tid + i * 256;
        int ww = e >> 7, ci = e & 127;
        xp[((size_t)(n * 30 + h + 1) * 30 + (ww + 1)) * 128 + ci] = f2bf(xs[ci][ww]);
    }
    if (tid < 224) {
        int grp = tid / 28, ww = tid - grp * 28;
        float a = 0.f;
        #pragma unroll
        for (int ci = grp * 16; ci < grp * 16 + 16; ++ci) a = fmaf(xs[ci][ww], xs[ci][ww], a);
        part[grp][ww] = a;
    }
    __syncthreads();
    if (tid < 28) {
        float a = 0.f;
        #pragma unroll
        for (int g = 0; g < 8; ++g) a += part[g][tid];
        s[n * 900 + (h + 1) * 30 + (tid + 1)] = a;
    }
}

// ---- MFMA implicit GEMM: BM=128, BN=64, 4 waves (2x2 of 64x32) ----
// A-slab resident in LDS (staged once, 10 rows); barrier-free K-loop with
// 1-step register prefetch + setprio around MFMA; coalesced epilogue.
__global__ __launch_bounds__(256, 2) void econv(
        const unsigned short* __restrict__ xp, const unsigned short* __restrict__ wp,
        const float* __restrict__ s, float* __restrict__ y, float* __restrict__ stats) {
    __shared__ unsigned short slab[SLAB_CHUNKS * 8];   // 77,824 B: 10 padded rows
    __shared__ float t1s[128];

    const int tid = threadIdx.x;
    // XCD-aware bijective swizzle (784 = 8*98)
    int bid = blockIdx.x;
    int swz = (bid & 7) * 98 + (bid >> 3);
    const int nb = swz & 3;
    const int mb = swz >> 2;
    const int gblock = mb * 128;
    const int nblock = nb * 64;
    const int ng0 = nb * 4;

    // slab covers global padded rows GR0..GR0+9 (crossing blocks need 10)
    const int n0  = gblock / 784;
    const int p0  = gblock - n0 * 784;
    const int GR0 = n0 * 30 + p0 / 28;
    const unsigned short* slabg = xp + (size_t)GR0 * 30 * 128;

    // stage slab once: linear LDS dest, source pre-swizzled.
    // slot sl of pixel Q holds source chunk c = (sl&8)|((sl&7)^(Q&7)).
    #pragma unroll
    for (int i = 0; i < 19; ++i) {
        int sc = tid + i * 256;
        int Q = sc >> 4, sl = sc & 15;
        int c = (sl & 8) | ((sl & 7) ^ (Q & 7));
        gload_lds16(slabg + (size_t)(Q * 16 + c) * 8, &slab[sc * 8]);
    }

    // t1 = 3x3 box of padded per-pixel sum of x^2
    if (tid < 128) {
        int g = gblock + tid; int n = g / 784, p = g - n * 784;
        int h = p / 28, wq = p - h * 28;
        const float* sb = s + n * 900 + h * 30 + wq;
        t1s[tid] = (sb[0] + sb[1] + sb[2]) + (sb[30] + sb[31] + sb[32]) + (sb[60] + sb[61] + sb[62]);
    }

    const int lane = tid & 63;
    const int wid  = tid >> 6;
    const int wm = wid >> 1, wn = wid & 1;
    const int l15 = lane & 15, l16 = lane >> 4;

    // per-lane slab pixel index (3x3 window top-left) for each fm row
    int Pp[4];
    #pragma unroll
    for (int fm = 0; fm < 4; ++fm) {
        int g = gblock + wm * 64 + fm * 16 + l15;
        int n = g / 784, p = g - n * 784;
        int h = p / 28, c = p - h * 28;
        Pp[fm] = (n * 30 + h - GR0) * 30 + c;
    }
    // per-lane B base: each wave's frag read is 1KB contiguous
    const unsigned short* wpl = wp + (size_t)((ng0 + wn * 2) * 64 + l16 * 16 + l15) * 8;

    f32x4 acc[4][2];
    #pragma unroll
    for (int a_ = 0; a_ < 4; ++a_)
        #pragma unroll
        for (int b_ = 0; b_ < 2; ++b_) acc[a_][b_] = (f32x4){0.f, 0.f, 0.f, 0.f};

    __syncthreads();   // slab + t1s ready; no barriers in K-loop

#define LOADK(ks, A, B) {                                                    \
    const int tap_ = (ks) >> 1, half_ = (ks) & 1;                            \
    const int toff_ = (tap_ / 3) * 30 + (tap_ % 3);                          \
    _Pragma("unroll") for (int q_ = 0; q_ < 2; ++q_) {                       \
        _Pragma("unroll") for (int fm_ = 0; fm_ < 4; ++fm_) {                \
            int P2_ = Pp[fm_] + toff_;                                       \
            int sl_ = half_ * 8 + ((q_ * 4 + l16) ^ (P2_ & 7));              \
            A[q_][fm_] = *(const bf16x8*)&slab[(P2_ * 16 + sl_) * 8];        \
        }                                                                    \
        const int K16_ = (tap_ * 4 + half_ * 2 + q_) * 16;                   \
        _Pragma("unroll") for (int fn_ = 0; fn_ < 2; ++fn_)                  \
            B[q_][fn_] = *(const bf16x8*)&wpl[(size_t)(K16_ + fn_) * 512];   \
    }                                                                        \
}

    bf16x8 aP[2][2][4], bP[2][2][2];
    LOADK(0, aP[0], bP[0]);
    #pragma unroll
    for (int ks = 0; ks < 18; ++ks) {
        const int cur = ks & 1;          // compile-time after unroll
        if (ks < 17) LOADK(ks + 1, aP[cur ^ 1], bP[cur ^ 1]);
        __builtin_amdgcn_s_setprio(1);   // T5: favor MFMA-issuing wave
        #pragma unroll
        for (int q = 0; q < 2; ++q)
            #pragma unroll
            for (int fm = 0; fm < 4; ++fm)
                #pragma unroll
                for (int fn = 0; fn < 2; ++fn)
                    acc[fm][fn] = __builtin_amdgcn_mfma_f32_16x16x32_bf16(
                        aP[cur][q][fm], bP[cur][q][fn], acc[fm][fn], 0, 0, 0);
        __builtin_amdgcn_s_setprio(0);
    }
#undef LOADK

    // ---- epilogue: coalesced via LDS transpose (slab reused) ----
    __syncthreads();   // all waves finished reading slab
    float* ldsT = (float*)slab;   // [64 co][132] floats = 33,792 B

    float sSum[2] = {0.f, 0.f}, sSq[2] = {0.f, 0.f};
    #pragma unroll
    for (int fm = 0; fm < 4; ++fm) {
        #pragma unroll
        for (int j = 0; j < 4; ++j) {
            int r = wm * 64 + fm * 16 + l16 * 4 + j;
            float t1v = t1s[r];
            #pragma unroll
            for (int fn = 0; fn < 2; ++fn) {
                float v = fmaf(2.f, acc[fm][fn][j], t1v);
                ldsT[(wn * 32 + fn * 16 + l15) * 132 + r] = v;
                float d = v - SHIFT_;
                sSum[fn] += d;
                sSq[fn] = fmaf(d, d, sSq[fn]);
            }
        }
    }
    __syncthreads();
    // coalesced store: thread reads f32x4 per (co, 4 consecutive pixels)
    #pragma unroll
    for (int i = 0; i < 8; ++i) {
        int idx = tid + i * 256;       // 0..2047
        int co  = idx >> 5;            // 0..63
        int r   = (idx & 31) * 4;      // block-local pixel, mult of 4
        int g   = gblock + r;
        int n = g / 784, p = g - n * 784;   // crossings at mult of 16: never split
        f32x4 v = *(const f32x4*)&ldsT[co * 132 + r];
        *(f32x4*)&y[(size_t)n * 200704 + (size_t)(nblock + co) * 784 + p] = v;
    }

    #pragma unroll
    for (int fn = 0; fn < 2; ++fn) {
        float a = sSum[fn], b2 = sSq[fn];
        a  += __shfl_xor(a, 16);  a  += __shfl_xor(a, 32);
        b2 += __shfl_xor(b2, 16); b2 += __shfl_xor(b2, 32);
        if (l16 == 0) {
            int co = nblock + wn * 32 + fn * 16 + l15;
            atomicAdd(&stats[co], a);
            atomicAdd(&stats[256 + co], b2);
        }
    }
}

__global__ __launch_bounds__(256) void bn_apply(
        float* __restrict__ y, const float* __restrict__ stats,
        const float* __restrict__ gamma, const float* __restrict__ beta) {
    const int TOTAL4 = NB_ * CO_ * NPIX / 4;
    int i4 = blockIdx.x * 256 + threadIdx.x;
    if (i4 >= TOTAL4) return;
    int c = (i4 / (NPIX / 4)) & (CO_ - 1);
    float su = stats[c];
    float s2 = stats[CO_ + c];
    const float invM = 1.0f / (float)M_TOT;
    float ms   = su * invM;
    float var  = fmaf(-ms, ms, s2 * invM);
    float mean = SHIFT_ + ms;
    float scale = rsqrtf(var + BN_EPS) * gamma[c];
    float bias  = beta[c] - mean * scale;
    f32x4 v = ((const f32x4*)y)[i4];
    v.x = fmaf(v.x, scale, bias);
    v.y = fmaf(v.y, scale, bias);
    v.z = fmaf(v.z, scale, bias);
    v.w = fmaf(v.w, scale, bias);
    ((f32x4*)y)[i4] = v;
}

extern "C" void kernel_launch(void* const* d_in, const int* in_sizes, int n_in,
                              void* d_out, int out_size, void* d_ws, size_t ws_size,
                              hipStream_t stream) {
    const float* x     = (const float*)d_in[0];
    const float* w     = (const float*)d_in[1];
    const float* gamma = (const float*)d_in[2];
    const float* beta  = (const float*)d_in[3];
    float* y = (float*)d_out;

    char* ws = (char*)d_ws;
    unsigned short* xp    = (unsigned short*)(ws);
    float*          s     = (float*)(ws + S_OFF);
    float*          stats = (float*)(ws + ST_OFF);
    unsigned short* wp    = (unsigned short*)(ws + WP_OFF);

    pack_all<<<2048, 256, 0, stream>>>(x, xp, s, w, wp, stats);
    econv<<<784, 256, 0, stream>>>(xp, wp, s, y, stats);
    bn_apply<<<(NB_ * CO_ * NPIX / 4 + 255) / 256, 256, 0, stream>>>(y, stats, gamma, beta);
}

// Round 18
// 44.373 us; speedup vs baseline: 2.4375x; 1.0099x over previous
//
#include <hip/hip_runtime.h>

// EuclidConv + BatchNorm (training stats), fp32 in/out.
// y = 2*conv(x,w) + t1 (+t2 cancels in BN).  bf16 MFMA implicit GEMM:
//   M=25088 pixels, N=256 chans, K=9 taps*128 ci.
// Round 18: r17 base + ONE delta: B-prefetch deepened to 2 steps (ring of 3).
// Mechanism: B loads hit L2 (~200-300cy) but 1-step MFMA cover is only
// ~80-160cy -> exposed latency each K-step. A stays 1-deep (LDS ~120cy).

typedef short  bf16x8 __attribute__((ext_vector_type(8)));
typedef float  f32x4  __attribute__((ext_vector_type(4)));

#define NPIX   784
#define CI_    128
#define CO_    256
#define NB_    32
#define M_     25088
#define SHIFT_ 1152.0f
#define BN_EPS 1e-5f
#define M_TOT  25088

// ws layout (bytes): xp [32][30][30][128] bf16 = 7,372,800 ; s [32][30][30] f32 ;
// stats [2][256] f32 ; wp [36][16][4][16][8] bf16 = 589,824 (round-2 layout)
#define S_OFF   7372800
#define ST_OFF  7488000
#define WP_OFF  7490048

#define SLAB_CHUNKS 4864          // 19*256; >= 10 rows * 30 * 16 = 4800

__device__ __forceinline__ unsigned short f2bf(float f) {
    unsigned int u = __float_as_uint(f);
    unsigned int r = (u + 0x7FFFu + ((u >> 16) & 1u)) >> 16;
    return (unsigned short)r;
}

__device__ __forceinline__ void gload_lds16(const void* gsrc, void* ldst) {
    __builtin_amdgcn_global_load_lds(
        (const __attribute__((address_space(1))) void*)gsrc,
        (__attribute__((address_space(3))) void*)ldst, 16, 0, 0);
}

// border pixel bp (0..115 within image): padded (row,col) of the zero ring
__device__ __forceinline__ int border_px(int b) {
    if (b < 30)  return 0 * 30 + b;              // top row, cols 0..29
    if (b < 60)  return 29 * 30 + (b - 30);      // bottom row
    if (b < 88)  return (1 + (b - 60)) * 30 + 0; // left col, rows 1..28
    return (1 + (b - 88)) * 30 + 29;             // right col
}

// ---- merged pack: blocks 0..895 pack_x; blocks 896..2047 pack_w + zeroing ----
__global__ __launch_bounds__(256) void pack_all(
        const float* __restrict__ x, unsigned short* __restrict__ xp,
        float* __restrict__ s, const float* __restrict__ w,
        unsigned short* __restrict__ wp, float* __restrict__ stats) {
    const int tid = threadIdx.x;

    if (blockIdx.x >= 896) {
        // ---- pack_w path (r14-verified) ----
        int o = (blockIdx.x - 896) * 256 + tid;  // < 294912
        {   // weight repack: wp[kblk(36)][ng(16)][kb(4)][cc(16)][k8(8)]
            int k8   = o & 7;
            int cc   = (o >> 3) & 15;
            int kb   = (o >> 7) & 3;
            int ng   = (o >> 9) & 15;
            int kblk = o >> 13;                  // 0..35
            int tap  = kblk >> 2;
            int ci   = (kblk & 3) * 32 + kb * 8 + k8;
            int co   = ng * 16 + cc;
            wp[o] = f2bf(w[(size_t)(co * 128 + ci) * 9 + tap]);
        }
        if (o < 3712 * 16) {                     // xp border zeroing (16B chunks)
            int bp = o >> 4, part = o & 15;
            int n = bp / 116, b = bp - n * 116;
            size_t px = (size_t)n * 900 + border_px(b);
            *(f32x4*)&xp[px * 128 + part * 8] = (f32x4){0.f, 0.f, 0.f, 0.f};
        } else if (o < 3712 * 16 + 3712) {       // s border zeroing
            int bp = o - 3712 * 16;
            int n = bp / 116, b = bp - n * 116;
            s[n * 900 + border_px(b)] = 0.f;
        } else if (o < 3712 * 16 + 3712 + 512) { // stats zeroing
            stats[o - (3712 * 16 + 3712)] = 0.f;
        }
        return;
    }

    // ---- pack_x path (r14-verified) ----
    const int n = blockIdx.x / 28, h = blockIdx.x % 28;
    __shared__ float xs[128][29];
    __shared__ float part[8][28];

    #pragma unroll
    for (int i = 0; i < 14; ++i) {
        int e = tid + i * 256;
        int ci = e / 28, ww = e - ci * 28;
        xs[ci][ww] = x[(size_t)(n * 128 + ci) * 784 + h * 28 + ww];
    }
    __syncthreads();
    #pragma unroll
    for (int i = 0; i < 14; ++i) {
        int e = tid + i * 256;
        int ww = e >> 7, ci = e & 127;
        xp[((size_t)(n * 30 + h + 1) * 30 + (ww + 1)) * 128 + ci] = f2bf(xs[ci][ww]);
    }
    if (tid < 224) {
        int grp = tid / 28, ww = tid - grp * 28;
        float a = 0.f;
        #pragma unroll
        for (int ci = grp * 16; ci < grp * 16 + 16; ++ci) a = fmaf(xs[ci][ww], xs[ci][ww], a);
        part[grp][ww] = a;
    }
    __syncthreads();
    if (tid < 28) {
        float a = 0.f;
        #pragma unroll
        for (int g = 0; g < 8; ++g) a += part[g][tid];
        s[n * 900 + (h + 1) * 30 + (tid + 1)] = a;
    }
}

// ---- MFMA implicit GEMM: BM=128, BN=64, 4 waves (2x2 of 64x32) ----
// A-slab resident in LDS (staged once, 10 rows); barrier-free K-loop with
// A 1-deep / B 2-deep register prefetch + setprio; coalesced epilogue.
__global__ __launch_bounds__(256, 2) void econv(
        const unsigned short* __restrict__ xp, const unsigned short* __restrict__ wp,
        const float* __restrict__ s, float* __restrict__ y, float* __restrict__ stats) {
    __shared__ unsigned short slab[SLAB_CHUNKS * 8];   // 77,824 B: 10 padded rows
    __shared__ float t1s[128];

    const int tid = threadIdx.x;
    // XCD-aware bijective swizzle (784 = 8*98)
    int bid = blockIdx.x;
    int swz = (bid & 7) * 98 + (bid >> 3);
    const int nb = swz & 3;
    const int mb = swz >> 2;
    const int gblock = mb * 128;
    const int nblock = nb * 64;
    const int ng0 = nb * 4;

    // slab covers global padded rows GR0..GR0+9 (crossing blocks need 10)
    const int n0  = gblock / 784;
    const int p0  = gblock - n0 * 784;
    const int GR0 = n0 * 30 + p0 / 28;
    const unsigned short* slabg = xp + (size_t)GR0 * 30 * 128;

    // stage slab once: linear LDS dest, source pre-swizzled.
    // slot sl of pixel Q holds source chunk c = (sl&8)|((sl&7)^(Q&7)).
    #pragma unroll
    for (int i = 0; i < 19; ++i) {
        int sc = tid + i * 256;
        int Q = sc >> 4, sl = sc & 15;
        int c = (sl & 8) | ((sl & 7) ^ (Q & 7));
        gload_lds16(slabg + (size_t)(Q * 16 + c) * 8, &slab[sc * 8]);
    }

    // t1 = 3x3 box of padded per-pixel sum of x^2
    if (tid < 128) {
        int g = gblock + tid; int n = g / 784, p = g - n * 784;
        int h = p / 28, wq = p - h * 28;
        const float* sb = s + n * 900 + h * 30 + wq;
        t1s[tid] = (sb[0] + sb[1] + sb[2]) + (sb[30] + sb[31] + sb[32]) + (sb[60] + sb[61] + sb[62]);
    }

    const int lane = tid & 63;
    const int wid  = tid >> 6;
    const int wm = wid >> 1, wn = wid & 1;
    const int l15 = lane & 15, l16 = lane >> 4;

    // per-lane slab pixel index (3x3 window top-left) for each fm row
    int Pp[4];
    #pragma unroll
    for (int fm = 0; fm < 4; ++fm) {
        int g = gblock + wm * 64 + fm * 16 + l15;
        int n = g / 784, p = g - n * 784;
        int h = p / 28, c = p - h * 28;
        Pp[fm] = (n * 30 + h - GR0) * 30 + c;
    }
    // per-lane B base: each wave's frag read is 1KB contiguous
    const unsigned short* wpl = wp + (size_t)((ng0 + wn * 2) * 64 + l16 * 16 + l15) * 8;

    f32x4 acc[4][2];
    #pragma unroll
    for (int a_ = 0; a_ < 4; ++a_)
        #pragma unroll
        for (int b_ = 0; b_ < 2; ++b_) acc[a_][b_] = (f32x4){0.f, 0.f, 0.f, 0.f};

    __syncthreads();   // slab + t1s ready; no barriers in K-loop

#define LOADA(ks, A) {                                                       \
    const int tap_ = (ks) >> 1, half_ = (ks) & 1;                            \
    const int toff_ = (tap_ / 3) * 30 + (tap_ % 3);                          \
    _Pragma("unroll") for (int q_ = 0; q_ < 2; ++q_)                         \
        _Pragma("unroll") for (int fm_ = 0; fm_ < 4; ++fm_) {                \
            int P2_ = Pp[fm_] + toff_;                                       \
            int sl_ = half_ * 8 + ((q_ * 4 + l16) ^ (P2_ & 7));              \
            A[q_][fm_] = *(const bf16x8*)&slab[(P2_ * 16 + sl_) * 8];        \
        }                                                                    \
}
#define LOADB(ks, B) {                                                       \
    const int tap_ = (ks) >> 1, half_ = (ks) & 1;                            \
    _Pragma("unroll") for (int q_ = 0; q_ < 2; ++q_) {                       \
        const int K16_ = (tap_ * 4 + half_ * 2 + q_) * 16;                   \
        _Pragma("unroll") for (int fn_ = 0; fn_ < 2; ++fn_)                  \
            B[q_][fn_] = *(const bf16x8*)&wpl[(size_t)(K16_ + fn_) * 512];   \
    }                                                                        \
}

    bf16x8 aP[2][2][4], bP[3][2][2];
    LOADB(0, bP[0]);
    LOADB(1, bP[1]);
    LOADA(0, aP[0]);
    #pragma unroll
    for (int ks = 0; ks < 18; ++ks) {
        const int cur  = ks & 1;         // compile-time after unroll
        const int bcur = ks % 3;
        if (ks < 17) LOADA(ks + 1, aP[cur ^ 1]);
        if (ks < 16) LOADB(ks + 2, bP[(ks + 2) % 3]);
        __builtin_amdgcn_s_setprio(1);   // T5: favor MFMA-issuing wave
        #pragma unroll
        for (int q = 0; q < 2; ++q)
            #pragma unroll
            for (int fm = 0; fm < 4; ++fm)
                #pragma unroll
                for (int fn = 0; fn < 2; ++fn)
                    acc[fm][fn] = __builtin_amdgcn_mfma_f32_16x16x32_bf16(
                        aP[cur][q][fm], bP[bcur][q][fn], acc[fm][fn], 0, 0, 0);
        __builtin_amdgcn_s_setprio(0);
    }
#undef LOADA
#undef LOADB

    // ---- epilogue: coalesced via LDS transpose (slab reused) ----
    __syncthreads();   // all waves finished reading slab
    float* ldsT = (float*)slab;   // [64 co][132] floats = 33,792 B

    float sSum[2] = {0.f, 0.f}, sSq[2] = {0.f, 0.f};
    #pragma unroll
    for (int fm = 0; fm < 4; ++fm) {
        #pragma unroll
        for (int j = 0; j < 4; ++j) {
            int r = wm * 64 + fm * 16 + l16 * 4 + j;
            float t1v = t1s[r];
            #pragma unroll
            for (int fn = 0; fn < 2; ++fn) {
                float v = fmaf(2.f, acc[fm][fn][j], t1v);
                ldsT[(wn * 32 + fn * 16 + l15) * 132 + r] = v;
                float d = v - SHIFT_;
                sSum[fn] += d;
                sSq[fn] = fmaf(d, d, sSq[fn]);
            }
        }
    }
    __syncthreads();
    // coalesced store: thread reads f32x4 per (co, 4 consecutive pixels)
    #pragma unroll
    for (int i = 0; i < 8; ++i) {
        int idx = tid + i * 256;       // 0..2047
        int co  = idx >> 5;            // 0..63
        int r   = (idx & 31) * 4;      // block-local pixel, mult of 4
        int g   = gblock + r;
        int n = g / 784, p = g - n * 784;   // crossings at mult of 16: never split
        f32x4 v = *(const f32x4*)&ldsT[co * 132 + r];
        *(f32x4*)&y[(size_t)n * 200704 + (size_t)(nblock + co) * 784 + p] = v;
    }

    #pragma unroll
    for (int fn = 0; fn < 2; ++fn) {
        float a = sSum[fn], b2 = sSq[fn];
        a  += __shfl_xor(a, 16);  a  += __shfl_xor(a, 32);
        b2 += __shfl_xor(b2, 16); b2 += __shfl_xor(b2, 32);
        if (l16 == 0) {
            int co = nblock + wn * 32 + fn * 16 + l15;
            atomicAdd(&stats[co], a);
            atomicAdd(&stats[256 + co], b2);
        }
    }
}

__global__ __launch_bounds__(256) void bn_apply(
        float* __restrict__ y, const float* __restrict__ stats,
        const float* __restrict__ gamma, const float* __restrict__ beta) {
    const int TOTAL4 = NB_ * CO_ * NPIX / 4;
    int i4 = blockIdx.x * 256 + threadIdx.x;
    if (i4 >= TOTAL4) return;
    int c = (i4 / (NPIX / 4)) & (CO_ - 1);
    float su = stats[c];
    float s2 = stats[CO_ + c];
    const float invM = 1.0f / (float)M_TOT;
    float ms   = su * invM;
    float var  = fmaf(-ms, ms, s2 * invM);
    float mean = SHIFT_ + ms;
    float scale = rsqrtf(var + BN_EPS) * gamma[c];
    float bias  = beta[c] - mean * scale;
    f32x4 v = ((const f32x4*)y)[i4];
    v.x = fmaf(v.x, scale, bias);
    v.y = fmaf(v.y, scale, bias);
    v.z = fmaf(v.z, scale, bias);
    v.w = fmaf(v.w, scale, bias);
    ((f32x4*)y)[i4] = v;
}

extern "C" void kernel_launch(void* const* d_in, const int* in_sizes, int n_in,
                              void* d_out, int out_size, void* d_ws, size_t ws_size,
                              hipStream_t stream) {
    const float* x     = (const float*)d_in[0];
    const float* w     = (const float*)d_in[1];
    const float* gamma = (const float*)d_in[2];
    const float* beta  = (const float*)d_in[3];
    float* y = (float*)d_out;

    char* ws = (char*)d_ws;
    unsigned short* xp    = (unsigned short*)(ws);
    float*          s     = (float*)(ws + S_OFF);
    float*          stats = (float*)(ws + ST_OFF);
    unsigned short* wp    = (unsigned short*)(ws + WP_OFF);

    pack_all<<<2048, 256, 0, stream>>>(x, xp, s, w, wp, stats);
    econv<<<784, 256, 0, stream>>>(xp, wp, s, y, stats);
    bn_apply<<<(NB_ * CO_ * NPIX / 4 + 255) / 256, 256, 0, stream>>>(y, stats, gamma, beta);
}

// Round 19
// 43.492 us; speedup vs baseline: 2.4869x; 1.0203x over previous
//
#include <hip/hip_runtime.h>

// EuclidConv + BatchNorm (training stats), fp32 in/out.
// y = 2*conv(x,w) + t1 (+t2 cancels in BN).  bf16 MFMA implicit GEMM:
//   M=25088 pixels, N=256 chans, K=9 taps*128 ci.
// Round 19: r18 base + bf16 pre-BN intermediate (stores d = y-SHIFT as bf16):
// saves 26MB of HBM round-trip (~4us). Guarded by ws_size — falls back to the
// verified fp32 path if workspace can't hold ybf. Stats still fp32-exact.

typedef short  bf16x8 __attribute__((ext_vector_type(8)));
typedef float  f32x4  __attribute__((ext_vector_type(4)));
typedef unsigned int u32x4 __attribute__((ext_vector_type(4)));

#define NPIX   784
#define CI_    128
#define CO_    256
#define NB_    32
#define M_     25088
#define SHIFT_ 1152.0f
#define BN_EPS 1e-5f
#define M_TOT  25088

// ws layout (bytes): xp [32][30][30][128] bf16 = 7,372,800 ; s [32][30][30] f32 ;
// stats [2][256] f32 ; wp bf16 = 589,824 ; ybf [32][256][784] bf16 = 12,845,056
#define S_OFF   7372800
#define ST_OFF  7488000
#define WP_OFF  7490048
#define YBF_OFF 8079872
#define WS_NEED (YBF_OFF + 12845056)

#define SLAB_CHUNKS 4864          // 19*256; >= 10 rows * 30 * 16 = 4800

__device__ __forceinline__ unsigned short f2bf(float f) {
    unsigned int u = __float_as_uint(f);
    unsigned int r = (u + 0x7FFFu + ((u >> 16) & 1u)) >> 16;
    return (unsigned short)r;
}

__device__ __forceinline__ void gload_lds16(const void* gsrc, void* ldst) {
    __builtin_amdgcn_global_load_lds(
        (const __attribute__((address_space(1))) void*)gsrc,
        (__attribute__((address_space(3))) void*)ldst, 16, 0, 0);
}

// border pixel bp (0..115 within image): padded (row,col) of the zero ring
__device__ __forceinline__ int border_px(int b) {
    if (b < 30)  return 0 * 30 + b;
    if (b < 60)  return 29 * 30 + (b - 30);
    if (b < 88)  return (1 + (b - 60)) * 30 + 0;
    return (1 + (b - 88)) * 30 + 29;
}

// ---- merged pack: blocks 0..895 pack_x; blocks 896..2047 pack_w + zeroing ----
__global__ __launch_bounds__(256) void pack_all(
        const float* __restrict__ x, unsigned short* __restrict__ xp,
        float* __restrict__ s, const float* __restrict__ w,
        unsigned short* __restrict__ wp, float* __restrict__ stats) {
    const int tid = threadIdx.x;

    if (blockIdx.x >= 896) {
        int o = (blockIdx.x - 896) * 256 + tid;  // < 294912
        {   // weight repack: wp[kblk(36)][ng(16)][kb(4)][cc(16)][k8(8)]
            int k8   = o & 7;
            int cc   = (o >> 3) & 15;
            int kb   = (o >> 7) & 3;
            int ng   = (o >> 9) & 15;
            int kblk = o >> 13;                  // 0..35
            int tap  = kblk >> 2;
            int ci   = (kblk & 3) * 32 + kb * 8 + k8;
            int co   = ng * 16 + cc;
            wp[o] = f2bf(w[(size_t)(co * 128 + ci) * 9 + tap]);
        }
        if (o < 3712 * 16) {                     // xp border zeroing (16B chunks)
            int bp = o >> 4, part = o & 15;
            int n = bp / 116, b = bp - n * 116;
            size_t px = (size_t)n * 900 + border_px(b);
            *(f32x4*)&xp[px * 128 + part * 8] = (f32x4){0.f, 0.f, 0.f, 0.f};
        } else if (o < 3712 * 16 + 3712) {       // s border zeroing
            int bp = o - 3712 * 16;
            int n = bp / 116, b = bp - n * 116;
            s[n * 900 + border_px(b)] = 0.f;
        } else if (o < 3712 * 16 + 3712 + 512) { // stats zeroing
            stats[o - (3712 * 16 + 3712)] = 0.f;
        }
        return;
    }

    // ---- pack_x path (r14-verified) ----
    const int n = blockIdx.x / 28, h = blockIdx.x % 28;
    __shared__ float xs[128][29];
    __shared__ float part[8][28];

    #pragma unroll
    for (int i = 0; i < 14; ++i) {
        int e = tid + i * 256;
        int ci = e / 28, ww = e - ci * 28;
        xs[ci][ww] = x[(size_t)(n * 128 + ci) * 784 + h * 28 + ww];
    }
    __syncthreads();
    #pragma unroll
    for (int i = 0; i < 14; ++i) {
        int e = tid + i * 256;
        int ww = e >> 7, ci = e & 127;
        xp[((size_t)(n * 30 + h + 1) * 30 + (ww + 1)) * 128 + ci] = f2bf(xs[ci][ww]);
    }
    if (tid < 224) {
        int grp = tid / 28, ww = tid - grp * 28;
        float a = 0.f;
        #pragma unroll
        for (int ci = grp * 16; ci < grp * 16 + 16; ++ci) a = fmaf(xs[ci][ww], xs[ci][ww], a);
        part[grp][ww] = a;
    }
    __syncthreads();
    if (tid < 28) {
        float a = 0.f;
        #pragma unroll
        for (int g = 0; g < 8; ++g) a += part[g][tid];
        s[n * 900 + (h + 1) * 30 + (tid + 1)] = a;
    }
}

// ---- MFMA implicit GEMM: BM=128, BN=64, 4 waves (2x2 of 64x32) ----
// r18-verified body; epilogue stores fp32 y (BFOUT=0) or bf16 d (BFOUT=1).
template <int BFOUT>
__global__ __launch_bounds__(256, 2) void econv_t(
        const unsigned short* __restrict__ xp, const unsigned short* __restrict__ wp,
        const float* __restrict__ s, float* __restrict__ y,
        unsigned short* __restrict__ ybf, float* __restrict__ stats) {
    __shared__ unsigned short slab[SLAB_CHUNKS * 8];   // 77,824 B: 10 padded rows
    __shared__ float t1s[128];

    const int tid = threadIdx.x;
    int bid = blockIdx.x;
    int swz = (bid & 7) * 98 + (bid >> 3);
    const int nb = swz & 3;
    const int mb = swz >> 2;
    const int gblock = mb * 128;
    const int nblock = nb * 64;
    const int ng0 = nb * 4;

    const int n0  = gblock / 784;
    const int p0  = gblock - n0 * 784;
    const int GR0 = n0 * 30 + p0 / 28;
    const unsigned short* slabg = xp + (size_t)GR0 * 30 * 128;

    #pragma unroll
    for (int i = 0; i < 19; ++i) {
        int sc = tid + i * 256;
        int Q = sc >> 4, sl = sc & 15;
        int c = (sl & 8) | ((sl & 7) ^ (Q & 7));
        gload_lds16(slabg + (size_t)(Q * 16 + c) * 8, &slab[sc * 8]);
    }

    if (tid < 128) {
        int g = gblock + tid; int n = g / 784, p = g - n * 784;
        int h = p / 28, wq = p - h * 28;
        const float* sb = s + n * 900 + h * 30 + wq;
        t1s[tid] = (sb[0] + sb[1] + sb[2]) + (sb[30] + sb[31] + sb[32]) + (sb[60] + sb[61] + sb[62]);
    }

    const int lane = tid & 63;
    const int wid  = tid >> 6;
    const int wm = wid >> 1, wn = wid & 1;
    const int l15 = lane & 15, l16 = lane >> 4;

    int Pp[4];
    #pragma unroll
    for (int fm = 0; fm < 4; ++fm) {
        int g = gblock + wm * 64 + fm * 16 + l15;
        int n = g / 784, p = g - n * 784;
        int h = p / 28, c = p - h * 28;
        Pp[fm] = (n * 30 + h - GR0) * 30 + c;
    }
    const unsigned short* wpl = wp + (size_t)((ng0 + wn * 2) * 64 + l16 * 16 + l15) * 8;

    f32x4 acc[4][2];
    #pragma unroll
    for (int a_ = 0; a_ < 4; ++a_)
        #pragma unroll
        for (int b_ = 0; b_ < 2; ++b_) acc[a_][b_] = (f32x4){0.f, 0.f, 0.f, 0.f};

    __syncthreads();   // slab + t1s ready; no barriers in K-loop

#define LOADA(ks, A) {                                                       \
    const int tap_ = (ks) >> 1, half_ = (ks) & 1;                            \
    const int toff_ = (tap_ / 3) * 30 + (tap_ % 3);                          \
    _Pragma("unroll") for (int q_ = 0; q_ < 2; ++q_)                         \
        _Pragma("unroll") for (int fm_ = 0; fm_ < 4; ++fm_) {                \
            int P2_ = Pp[fm_] + toff_;                                       \
            int sl_ = half_ * 8 + ((q_ * 4 + l16) ^ (P2_ & 7));              \
            A[q_][fm_] = *(const bf16x8*)&slab[(P2_ * 16 + sl_) * 8];        \
        }                                                                    \
}
#define LOADB(ks, B) {                                                       \
    const int tap_ = (ks) >> 1, half_ = (ks) & 1;                            \
    _Pragma("unroll") for (int q_ = 0; q_ < 2; ++q_) {                       \
        const int K16_ = (tap_ * 4 + half_ * 2 + q_) * 16;                   \
        _Pragma("unroll") for (int fn_ = 0; fn_ < 2; ++fn_)                  \
            B[q_][fn_] = *(const bf16x8*)&wpl[(size_t)(K16_ + fn_) * 512];   \
    }                                                                        \
}

    bf16x8 aP[2][2][4], bP[3][2][2];
    LOADB(0, bP[0]);
    LOADB(1, bP[1]);
    LOADA(0, aP[0]);
    #pragma unroll
    for (int ks = 0; ks < 18; ++ks) {
        const int cur  = ks & 1;
        const int bcur = ks % 3;
        if (ks < 17) LOADA(ks + 1, aP[cur ^ 1]);
        if (ks < 16) LOADB(ks + 2, bP[(ks + 2) % 3]);
        __builtin_amdgcn_s_setprio(1);   // T5
        #pragma unroll
        for (int q = 0; q < 2; ++q)
            #pragma unroll
            for (int fm = 0; fm < 4; ++fm)
                #pragma unroll
                for (int fn = 0; fn < 2; ++fn)
                    acc[fm][fn] = __builtin_amdgcn_mfma_f32_16x16x32_bf16(
                        aP[cur][q][fm], bP[bcur][q][fn], acc[fm][fn], 0, 0, 0);
        __builtin_amdgcn_s_setprio(0);
    }
#undef LOADA
#undef LOADB

    // ---- epilogue: coalesced via LDS transpose (slab reused) ----
    __syncthreads();
    float* ldsT = (float*)slab;   // [64 co][132] floats = 33,792 B

    float sSum[2] = {0.f, 0.f}, sSq[2] = {0.f, 0.f};
    #pragma unroll
    for (int fm = 0; fm < 4; ++fm) {
        #pragma unroll
        for (int j = 0; j < 4; ++j) {
            int r = wm * 64 + fm * 16 + l16 * 4 + j;
            float t1v = t1s[r];
            #pragma unroll
            for (int fn = 0; fn < 2; ++fn) {
                float v = fmaf(2.f, acc[fm][fn][j], t1v);
                float d = v - SHIFT_;
                ldsT[(wn * 32 + fn * 16 + l15) * 132 + r] = BFOUT ? d : v;
                sSum[fn] += d;
                sSq[fn] = fmaf(d, d, sSq[fn]);
            }
        }
    }
    __syncthreads();
    if constexpr (BFOUT) {
        // bf16 store: thread packs 8 consecutive pixels (16B per store)
        #pragma unroll
        for (int i = 0; i < 4; ++i) {
            int idx = tid + i * 256;       // 0..1023
            int co  = idx >> 4;            // 0..63
            int r   = (idx & 15) * 8;      // mult of 8; crossings at mult 16
            int g   = gblock + r;
            int n = g / 784, p = g - n * 784;
            const float* src = &ldsT[co * 132 + r];
            u32x4 pk;
            #pragma unroll
            for (int j = 0; j < 4; ++j) {
                unsigned int lo = f2bf(src[2 * j]);
                unsigned int hi = f2bf(src[2 * j + 1]);
                pk[j] = lo | (hi << 16);
            }
            *(u32x4*)&ybf[(size_t)n * 200704 + (size_t)(nblock + co) * 784 + p] = pk;
        }
    } else {
        #pragma unroll
        for (int i = 0; i < 8; ++i) {
            int idx = tid + i * 256;       // 0..2047
            int co  = idx >> 5;            // 0..63
            int r   = (idx & 31) * 4;      // mult of 4
            int g   = gblock + r;
            int n = g / 784, p = g - n * 784;
            f32x4 v = *(const f32x4*)&ldsT[co * 132 + r];
            *(f32x4*)&y[(size_t)n * 200704 + (size_t)(nblock + co) * 784 + p] = v;
        }
    }

    #pragma unroll
    for (int fn = 0; fn < 2; ++fn) {
        float a = sSum[fn], b2 = sSq[fn];
        a  += __shfl_xor(a, 16);  a  += __shfl_xor(a, 32);
        b2 += __shfl_xor(b2, 16); b2 += __shfl_xor(b2, 32);
        if (l16 == 0) {
            int co = nblock + wn * 32 + fn * 16 + l15;
            atomicAdd(&stats[co], a);
            atomicAdd(&stats[256 + co], b2);
        }
    }
}

__global__ __launch_bounds__(256) void bn_apply(
        float* __restrict__ y, const float* __restrict__ stats,
        const float* __restrict__ gamma, const float* __restrict__ beta) {
    const int TOTAL4 = NB_ * CO_ * NPIX / 4;
    int i4 = blockIdx.x * 256 + threadIdx.x;
    if (i4 >= TOTAL4) return;
    int c = (i4 / (NPIX / 4)) & (CO_ - 1);
    float su = stats[c];
    float s2 = stats[CO_ + c];
    const float invM = 1.0f / (float)M_TOT;
    float ms   = su * invM;
    float var  = fmaf(-ms, ms, s2 * invM);
    float mean = SHIFT_ + ms;
    float scale = rsqrtf(var + BN_EPS) * gamma[c];
    float bias  = beta[c] - mean * scale;
    f32x4 v = ((const f32x4*)y)[i4];
    v.x = fmaf(v.x, scale, bias);
    v.y = fmaf(v.y, scale, bias);
    v.z = fmaf(v.z, scale, bias);
    v.w = fmaf(v.w, scale, bias);
    ((f32x4*)y)[i4] = v;
}

// bf16 variant: reads centered bf16 d, writes fp32 out; SHIFT folded into bias.
__global__ __launch_bounds__(256) void bn_apply_bf(
        const unsigned short* __restrict__ ybf, const float* __restrict__ stats,
        const float* __restrict__ gamma, const float* __restrict__ beta,
        float* __restrict__ y) {
    int i8 = blockIdx.x * 256 + threadIdx.x;     // < 802816 (exactly 3136*256)
    int c = (i8 / 98) & (CO_ - 1);               // 98 = 784/8 groups per channel
    float su = stats[c];
    float s2 = stats[CO_ + c];
    const float invM = 1.0f / (float)M_TOT;
    float ms   = su * invM;
    float var  = fmaf(-ms, ms, s2 * invM);
    float scale = rsqrtf(var + BN_EPS) * gamma[c];
    float bias  = beta[c] - ms * scale;          // out = d*scale + bias
    u32x4 pk = *(const u32x4*)&ybf[(size_t)i8 * 8];
    float o[8];
    #pragma unroll
    for (int j = 0; j < 4; ++j) {
        o[2 * j]     = fmaf(__uint_as_float(pk[j] << 16), scale, bias);
        o[2 * j + 1] = fmaf(__uint_as_float(pk[j] & 0xffff0000u), scale, bias);
    }
    float* dst = &y[(size_t)i8 * 8];
    ((f32x4*)dst)[0] = (f32x4){o[0], o[1], o[2], o[3]};
    ((f32x4*)dst)[1] = (f32x4){o[4], o[5], o[6], o[7]};
}

extern "C" void kernel_launch(void* const* d_in, const int* in_sizes, int n_in,
                              void* d_out, int out_size, void* d_ws, size_t ws_size,
                              hipStream_t stream) {
    const float* x     = (const float*)d_in[0];
    const float* w     = (const float*)d_in[1];
    const float* gamma = (const float*)d_in[2];
    const float* beta  = (const float*)d_in[3];
    float* y = (float*)d_out;

    char* ws = (char*)d_ws;
    unsigned short* xp    = (unsigned short*)(ws);
    float*          s     = (float*)(ws + S_OFF);
    float*          stats = (float*)(ws + ST_OFF);
    unsigned short* wp    = (unsigned short*)(ws + WP_OFF);
    unsigned short* ybf   = (unsigned short*)(ws + YBF_OFF);

    pack_all<<<2048, 256, 0, stream>>>(x, xp, s, w, wp, stats);
    if (ws_size >= (size_t)WS_NEED) {
        econv_t<1><<<784, 256, 0, stream>>>(xp, wp, s, y, ybf, stats);
        bn_apply_bf<<<3136, 256, 0, stream>>>(ybf, stats, gamma, beta, y);
    } else {
        econv_t<0><<<784, 256, 0, stream>>>(xp, wp, s, y, ybf, stats);
        bn_apply<<<(NB_ * CO_ * NPIX / 4 + 255) / 256, 256, 0, stream>>>(y, stats, gamma, beta);
    }
}